// Round 4
// baseline (722.570 us; speedup 1.0000x reference)
//
#include <hip/hip_runtime.h>
#include <hip/hip_bf16.h>
#include <math.h>

#define BB 16
#define IC 64
#define CH 128
#define LL 16384
#define KS 5
#define CAK 5
#define KCR 76
#define EPSV 1e-5f
#define NLT2 64           // psum/pmax partials per (b,c): 32 l-groups x 2 half-waves

typedef short bf16x8 __attribute__((ext_vector_type(8)));
typedef float f32x16 __attribute__((ext_vector_type(16)));

// ---- workspace layout (in floats) ----
#define OFF_WPACK 0                          // 81920 ushort = 40960 floats
#define OFF_BIAS2 40960                      // 128
#define OFF_PSUM  (OFF_BIAS2 + CH)           // 16*128*64 = 131072
#define OFF_PMAX  (OFF_PSUM + BB*CH*NLT2)
#define OFF_CM    (OFF_PMAX + BB*CH*NLT2)    // 2048
#define OFF_MASK  (OFF_CM + BB*CH)
#define OFF_HB    (OFF_MASK + BB*CH)         // halo buffer: 16*128*384 = 786432

__device__ __forceinline__ unsigned short f2bf(float f) {
    union { float f; unsigned u; } v; v.f = f;
    return (unsigned short)((v.u + 0x7FFFu + ((v.u >> 16) & 1u)) >> 16);
}
__device__ __forceinline__ float bf2f(unsigned short h) {
    union { unsigned u; float f; } v; v.u = ((unsigned)h) << 16;
    return v.f;
}
__device__ __forceinline__ unsigned short f2h(float f) {
    _Float16 h = (_Float16)f;
    return __builtin_bit_cast(unsigned short, h);
}
__device__ __forceinline__ float h2f(unsigned short u) {
    _Float16 h = __builtin_bit_cast(_Float16, u);
    return (float)h;
}

// ---------------------------------------------------------------------------
// Prep: fold BN scale into conv weights, split into bf16 hi/lo, pack in exact
// per-lane MFMA A-fragment order:
//   wpack[((((ver*2+ch2)*2+mt)*20+s)*64+ln)*8+j]
//     c = ch2*64 + mt*32 + (ln&31); kk = s>>2; i = (s&3)*16 + (ln>>5)*8 + j
// ---------------------------------------------------------------------------
__global__ void prep_kernel(const float* __restrict__ conv_w, const float* __restrict__ conv_b,
                            const float* __restrict__ bn_g, const float* __restrict__ bn_b,
                            const float* __restrict__ bn_m, const float* __restrict__ bn_v,
                            unsigned short* __restrict__ wpack, float* __restrict__ bias2)
{
    int e = blockIdx.x * 256 + threadIdx.x;
    if (e < 2 * 2 * 2 * 20 * 64 * 8) {
        int j    = e & 7;
        int ln   = (e >> 3) & 63;
        int rest = e >> 9;              // 0..159
        int s    = rest % 20;
        int mt   = (rest / 20) & 1;
        int ch2  = (rest / 40) & 1;
        int ver  = rest / 80;
        int c  = ch2 * 64 + mt * 32 + (ln & 31);
        int kk = s >> 2;
        int i  = (s & 3) * 16 + (ln >> 5) * 8 + j;
        float inv = bn_g[c] * rsqrtf(bn_v[c] + EPSV);
        float w = conv_w[(c * IC + i) * KS + kk] * inv;
        unsigned short h = f2bf(w);
        wpack[e] = (ver == 0) ? h : f2bf(w - bf2f(h));
    }
    if (e < CH) {
        float inv = bn_g[e] * rsqrtf(bn_v[e] + EPSV);
        bias2[e] = (conv_b[e] - bn_m[e]) * inv + bn_b[e];
    }
}

// ---------------------------------------------------------------------------
// Split-bf16 MFMA conv + BN + ReLU -> f (fp32, into d_out) + per-channel
// partial sum/max + boundary-halo copy for the fused downstream kernel.
// Block = 128c x 512l (4 tiles of 128l), 4 waves of (64c x 64l), LDS
// double-buffered (2-phase pipeline: compute tile t, then stage t+1).
// f = wh*xh + wh*xl + wl*xh  (fp32 MFMA accumulate).
// ---------------------------------------------------------------------------
__global__ __launch_bounds__(256, 2)
void conv_mfma_kernel(const float* __restrict__ x,
                      const unsigned short* __restrict__ wpack,
                      const float* __restrict__ bias2,
                      float* __restrict__ f,
                      float* __restrict__ psum, float* __restrict__ pmax,
                      float* __restrict__ hb)
{
    __shared__ unsigned short xs[2 * 136 * 128];   // 69,632 B (2 buffers)
    const int ltg = blockIdx.x;      // 0..31 (512-l group)
    const int b   = blockIdx.y;
    const int tid = threadIdx.x;
    const int ln  = tid & 63;
    const int wv  = __builtin_amdgcn_readfirstlane(tid >> 6);
    const int ibase = wv * 16;

    const float* xb = x + (size_t)b * (IC * LL);

    // stage-load group g (rows g*64+ln) for tile starting at l0t
    auto sld = [&](float* v, int l0t, int g) {
        int row = g * 64 + ln;
        int l   = l0t - 4 + row;
        bool vl = (row < 136) && (l >= 0) && (l < LL);
        #pragma unroll
        for (int q = 0; q < 16; ++q)
            v[q] = vl ? xb[(size_t)(ibase + q) * LL + l] : 0.0f;
    };
    // convert + swizzled ds_write of group g into buf
    auto swr = [&](const float* v, unsigned short* buf, int g) {
        int row = g * 64 + ln;
        if (row < 136) {
            int rs = row & 7;
            #pragma unroll
            for (int q2 = 0; q2 < 4; ++q2) {
                unsigned short h[4], lo[4];
                #pragma unroll
                for (int j = 0; j < 4; ++j) {
                    float vv = v[q2 * 4 + j];
                    h[j]  = f2bf(vv);
                    lo[j] = f2bf(vv - bf2f(h[j]));
                }
                int i0   = ibase + q2 * 4;
                int cc   = (i0 >> 3) ^ rs;
                int epos = row * 128 + cc * 8 + (i0 & 7);
                uint2 wh, wl;
                wh.x = (unsigned)h[0]  | ((unsigned)h[1]  << 16);
                wh.y = (unsigned)h[2]  | ((unsigned)h[3]  << 16);
                wl.x = (unsigned)lo[0] | ((unsigned)lo[1] << 16);
                wl.y = (unsigned)lo[2] | ((unsigned)lo[3] << 16);
                *(uint2*)&buf[epos]      = wh;
                *(uint2*)&buf[epos + 64] = wl;
            }
        }
    };

    const int ch2  = wv >> 1;   // c-half
    const int lh   = wv & 1;    // l-half within 128-l tile
    const int ln31 = ln & 31;
    const int hi   = ln >> 5;
    const int rowbase = lh * 64 + ln31 + 2;

    const unsigned short* wp  = wpack + (size_t)ln * 8;
    const unsigned short* pA0 = wp + (size_t)((ch2 * 2 + 0) * 20) * 512;       // wh, mt0
    const unsigned short* pA1 = wp + (size_t)((ch2 * 2 + 1) * 20) * 512;       // wh, mt1
    const unsigned short* pA2 = wp + (size_t)(((2 + ch2) * 2 + 0) * 20) * 512; // wl, mt0
    const unsigned short* pA3 = wp + (size_t)(((2 + ch2) * 2 + 1) * 20) * 512; // wl, mt1

    auto loadA = [&](bf16x8* Av, int s) {
        Av[0] = *(const bf16x8*)(pA0 + (size_t)s * 512);
        Av[1] = *(const bf16x8*)(pA1 + (size_t)s * 512);
        Av[2] = *(const bf16x8*)(pA2 + (size_t)s * 512);
        Av[3] = *(const bf16x8*)(pA3 + (size_t)s * 512);
    };
    auto loadB = [&](bf16x8* Bv, const unsigned short* buf, int s) {
        int kk = s >> 2, iq = s & 3;
        int r0 = rowbase + kk;
        int r1 = r0 + 32;
        int c0 = ((iq << 1) + hi) ^ (r0 & 7);
        int c1 = ((iq << 1) + hi) ^ (r1 & 7);
        Bv[0] = *(const bf16x8*)&buf[r0 * 128 + c0 * 8];        // bh, nt0
        Bv[1] = *(const bf16x8*)&buf[r0 * 128 + 64 + c0 * 8];   // bl, nt0
        Bv[2] = *(const bf16x8*)&buf[r1 * 128 + c1 * 8];        // bh, nt1
        Bv[3] = *(const bf16x8*)&buf[r1 * 128 + 64 + c1 * 8];   // bl, nt1
    };

    f32x16 acc[2][2];
    float sacc[2][16], macc[2][16];
    #pragma unroll
    for (int mt = 0; mt < 2; ++mt) {
        #pragma unroll
        for (int r = 0; r < 16; ++r) { sacc[mt][r] = 0.f; macc[mt][r] = 0.f; }
        #pragma unroll
        for (int nt = 0; nt < 2; ++nt)
            #pragma unroll
            for (int r = 0; r < 16; ++r) acc[mt][nt][r] = 0.0f;
    }

    auto compute = [&](const bf16x8* Av, const bf16x8* Bv) {
        acc[0][0] = __builtin_amdgcn_mfma_f32_32x32x16_bf16(Av[0], Bv[0], acc[0][0], 0, 0, 0);
        acc[1][0] = __builtin_amdgcn_mfma_f32_32x32x16_bf16(Av[1], Bv[0], acc[1][0], 0, 0, 0);
        acc[0][0] = __builtin_amdgcn_mfma_f32_32x32x16_bf16(Av[0], Bv[1], acc[0][0], 0, 0, 0);
        acc[1][0] = __builtin_amdgcn_mfma_f32_32x32x16_bf16(Av[1], Bv[1], acc[1][0], 0, 0, 0);
        acc[0][0] = __builtin_amdgcn_mfma_f32_32x32x16_bf16(Av[2], Bv[0], acc[0][0], 0, 0, 0);
        acc[1][0] = __builtin_amdgcn_mfma_f32_32x32x16_bf16(Av[3], Bv[0], acc[1][0], 0, 0, 0);
        acc[0][1] = __builtin_amdgcn_mfma_f32_32x32x16_bf16(Av[0], Bv[2], acc[0][1], 0, 0, 0);
        acc[1][1] = __builtin_amdgcn_mfma_f32_32x32x16_bf16(Av[1], Bv[2], acc[1][1], 0, 0, 0);
        acc[0][1] = __builtin_amdgcn_mfma_f32_32x32x16_bf16(Av[0], Bv[3], acc[0][1], 0, 0, 0);
        acc[1][1] = __builtin_amdgcn_mfma_f32_32x32x16_bf16(Av[1], Bv[3], acc[1][1], 0, 0, 0);
        acc[0][1] = __builtin_amdgcn_mfma_f32_32x32x16_bf16(Av[2], Bv[2], acc[0][1], 0, 0, 0);
        acc[1][1] = __builtin_amdgcn_mfma_f32_32x32x16_bf16(Av[3], Bv[2], acc[1][1], 0, 0, 0);
    };

    // epilogue for one mt-half of tile t: bias+relu, store f (+halo), accumulate
    auto epi = [&](int mt, int l0t) {
        #pragma unroll
        for (int nt = 0; nt < 2; ++nt) {
            int lg = l0t + lh * 64 + ln31 + nt * 32;
            int lm = lg & 255;
            bool hs = (lm < 3) || (lm >= 253);
            int hslot = (lg >> 8) * 6 + (lm < 3 ? lm : lm - 250);
            #pragma unroll
            for (int r = 0; r < 16; ++r) {
                int c = ch2 * 64 + mt * 32 + (r & 3) + 8 * (r >> 2) + 4 * hi;
                float fv = fmaxf(acc[mt][nt][r] + bias2[c], 0.0f);
                f[((size_t)(b * CH + c)) * LL + lg] = fv;
                if (hs) hb[((size_t)(b * CH + c)) * 384 + hslot] = fv;
                sacc[mt][r] += fv;
                macc[mt][r] = fmaxf(macc[mt][r], fv);
                acc[mt][nt][r] = 0.0f;
            }
        }
    };

    // ---- prologue: stage tile 0 ----
    {
        float sv[16];
        sld(sv, ltg * 512, 0); swr(sv, xs, 0);
        sld(sv, ltg * 512, 1); swr(sv, xs, 1);
        sld(sv, ltg * 512, 2); swr(sv, xs, 2);
    }
    __syncthreads();

    for (int t = 0; t < 4; ++t) {
        unsigned short* cb = xs + (t & 1) * (136 * 128);
        unsigned short* nb = xs + ((t + 1) & 1) * (136 * 128);
        const int l0t = ltg * 512 + t * 128;
        const bool more = (t < 3);

        bf16x8 Af[2][4], Bf[2][4];
        loadA(Af[0], 0); loadB(Bf[0], cb, 0);
        #pragma unroll
        for (int s = 0; s < 20; ++s) {
            if (s < 19) { loadA(Af[(s + 1) & 1], s + 1); loadB(Bf[(s + 1) & 1], cb, s + 1); }
            compute(Af[s & 1], Bf[s & 1]);
        }

        // stage t+1 interleaved with epilogue (loads issued after all A-loads,
        // so vmcnt waits in the slice loop never block on HBM staging)
        float sv[16];
        if (more) sld(sv, l0t + 128, 0);
        epi(0, l0t);
        if (more) { swr(sv, nb, 0); sld(sv, l0t + 128, 1); }
        epi(1, l0t);
        if (more) { swr(sv, nb, 1); sld(sv, l0t + 128, 2); }
        if (more) swr(sv, nb, 2);
        __syncthreads();
    }

    // ---- once per block: butterfly-reduce sacc/macc over 32 lanes, store ----
    #pragma unroll
    for (int mt = 0; mt < 2; ++mt) {
        #pragma unroll
        for (int r = 0; r < 16; ++r) {
            float s = sacc[mt][r];
            float m = macc[mt][r];
            #pragma unroll
            for (int off = 1; off <= 16; off <<= 1) {
                s += __shfl_xor(s, off, 64);
                m = fmaxf(m, __shfl_xor(m, off, 64));
            }
            if (ln31 == 0) {
                int c    = ch2 * 64 + mt * 32 + (r & 3) + 8 * (r >> 2) + 4 * hi;
                int slot = ltg * 2 + lh;
                psum[(b * CH + c) * NLT2 + slot] = s;
                pmax[(b * CH + c) * NLT2 + slot] = m;
            }
        }
    }
}

// ---------------------------------------------------------------------------
// Per-batch: finish L-reductions, channel attention, top-K mask (rank count,
// ties by lower index to match jax.lax.top_k). Grid: B x 128 threads.
// ---------------------------------------------------------------------------
__global__ void chan_kernel(const float* __restrict__ psum, const float* __restrict__ pmax,
                            const float* __restrict__ alpha, const float* __restrict__ beta,
                            const float* __restrict__ ca_w, const float* __restrict__ ca_b,
                            float* __restrict__ cm, float* __restrict__ maskv)
{
    int b = blockIdx.x;
    int c = threadIdx.x;   // 128
    const float* ps = psum + (b * CH + c) * NLT2;
    const float* pm = pmax + (b * CH + c) * NLT2;
    float s = 0.0f, m = 0.0f;
    for (int t = 0; t < NLT2; ++t) { s += ps[t]; m = fmaxf(m, pm[t]); }
    float favg = s * (1.0f / LL);
    float fadd = (alpha[0] + 0.5f) * favg + (beta[0] + 0.5f) * m;

    __shared__ float fa[CH];
    __shared__ float cms[CH];
    fa[c] = fadd;
    __syncthreads();

    float z = ca_b[0];
    #pragma unroll
    for (int k = 0; k < CAK; ++k) {
        int cc = c + k - 2;
        float v = (cc >= 0 && cc < CH) ? fa[cc] : 0.0f;
        z = fmaf(ca_w[k], v, z);
    }
    float cmv = 1.0f / (1.0f + expf(-z));
    cms[c] = cmv;
    __syncthreads();

    int rank = 0;
    for (int cc = 0; cc < CH; ++cc) {
        float o = cms[cc];
        rank += (o > cmv || (o == cmv && cc < c)) ? 1 : 0;
    }
    cm[b * CH + c] = cmv;
    maskv[b * CH + c] = (rank < KCR) ? 1.0f : 0.0f;
}

// ---------------------------------------------------------------------------
// Fused stats + gate + final. Block = (b, 256 l). Reads f (d_out) once,
// caches the tile as fp16 in LDS, computes per-l group stats (halo columns
// from the hb side-buffer -> no cross-block race), 7-tap gate conv + BN +
// ReLU + sigmoid in registers, then writes out = f*cm*(mask?A1:A2) in place.
// ---------------------------------------------------------------------------
__global__ __launch_bounds__(256, 2)
void sgf_kernel(float* fo, const float* __restrict__ hb,
                const float* __restrict__ cm, const float* __restrict__ maskv,
                const float* __restrict__ sa_w,
                const float* __restrict__ sabn_g, const float* __restrict__ sabn_b,
                const float* __restrict__ sabn_m, const float* __restrict__ sabn_v)
{
    __shared__ unsigned short f16[CH][256];   // 64 KiB fp16 tile cache
    __shared__ float st[4][262];
    __shared__ float cms[CH], mks[CH];
    const int g   = blockIdx.x;    // 0..63 (256-l tile)
    const int b   = blockIdx.y;
    const int l0  = g * 256;
    const int tid = threadIdx.x;
    if (tid < CH) { cms[tid] = cm[b * CH + tid]; mks[tid] = maskv[b * CH + tid]; }
    __syncthreads();

    for (int idx = tid; idx < 262; idx += 256) {
        int l = l0 - 3 + idx;
        float cmx = 0.f, csm = 0.f, smx = 0.f, ssm = 0.f;
        if (l >= 0 && l < LL) {
            bool inter = (idx >= 3) && (idx < 259);
            const float* fb  = fo + (size_t)b * CH * LL + l;
            int lm = l & 255;
            const float* hbb = hb + ((size_t)b * CH) * 384 + (l >> 8) * 6 + (lm < 3 ? lm : lm - 250);
            #pragma unroll 4
            for (int c = 0; c < CH; ++c) {
                float v;
                if (inter) {
                    v = fb[(size_t)c * LL];
                    f16[c][idx - 3] = f2h(v);
                } else {
                    v = hbb[(size_t)c * 384];
                }
                v *= cms[c];
                float mk = mks[c];
                float vs = v * mk;
                float vu = v - vs;
                cmx = fmaxf(cmx, vs);
                smx = fmaxf(smx, vu);
                csm += vs;
                ssm += vu;
            }
        }
        st[0][idx] = cmx;
        st[1][idx] = csm * (1.0f / KCR);
        st[2][idx] = smx;
        st[3][idx] = ssm * (1.0f / (CH - KCR));
    }
    __syncthreads();

    float inv = sabn_g[0] * rsqrtf(sabn_v[0] + EPSV);
    float bb2 = sabn_b[0] - sabn_m[0] * inv;
    float y1 = 0.f, y2 = 0.f;
    #pragma unroll
    for (int k = 0; k < 7; ++k) {
        float wm = sa_w[k], wa = sa_w[7 + k];
        y1 = fmaf(wm, st[0][tid + k], fmaf(wa, st[1][tid + k], y1));
        y2 = fmaf(wm, st[2][tid + k], fmaf(wa, st[3][tid + k], y2));
    }
    float t1 = fmaxf(y1 * inv + bb2, 0.f);
    float t2 = fmaxf(y2 * inv + bb2, 0.f);
    float A1 = 1.0f / (1.0f + expf(-t1));
    float A2 = 1.0f / (1.0f + expf(-t2));

    float* ob = fo + (size_t)b * CH * LL + l0 + tid;
    #pragma unroll 4
    for (int c = 0; c < CH; ++c) {
        float v = h2f(f16[c][tid]) * cms[c];
        float a = (mks[c] > 0.5f) ? A1 : A2;
        ob[(size_t)c * LL] = v * a;
    }
}

extern "C" void kernel_launch(void* const* d_in, const int* in_sizes, int n_in,
                              void* d_out, int out_size, void* d_ws, size_t ws_size,
                              hipStream_t stream)
{
    const float* x      = (const float*)d_in[0];
    const float* conv_w = (const float*)d_in[1];
    const float* conv_b = (const float*)d_in[2];
    const float* bn_g   = (const float*)d_in[3];
    const float* bn_b   = (const float*)d_in[4];
    const float* bn_m   = (const float*)d_in[5];
    const float* bn_v   = (const float*)d_in[6];
    const float* alpha  = (const float*)d_in[7];
    const float* beta   = (const float*)d_in[8];
    const float* ca_w   = (const float*)d_in[9];
    const float* ca_b   = (const float*)d_in[10];
    const float* sa_w   = (const float*)d_in[11];
    const float* sabn_g = (const float*)d_in[12];
    const float* sabn_b = (const float*)d_in[13];
    const float* sabn_m = (const float*)d_in[14];
    const float* sabn_v = (const float*)d_in[15];

    float* out = (float*)d_out;
    float* ws  = (float*)d_ws;

    unsigned short* wpack = (unsigned short*)(ws + OFF_WPACK);
    float* bias2 = ws + OFF_BIAS2;
    float* psum  = ws + OFF_PSUM;
    float* pmax  = ws + OFF_PMAX;
    float* cmv_  = ws + OFF_CM;
    float* mskv  = ws + OFF_MASK;
    float* hbp   = ws + OFF_HB;

    prep_kernel<<<320, 256, 0, stream>>>(conv_w, conv_b, bn_g, bn_b, bn_m, bn_v, wpack, bias2);

    conv_mfma_kernel<<<dim3(32, BB), 256, 0, stream>>>(x, wpack, bias2, out, psum, pmax, hbp);

    chan_kernel<<<BB, CH, 0, stream>>>(psum, pmax, alpha, beta, ca_w, ca_b, cmv_, mskv);

    sgf_kernel<<<dim3(64, BB), 256, 0, stream>>>(out, hbp, cmv_, mskv, sa_w,
                                                 sabn_g, sabn_b, sabn_m, sabn_v);
}

// Round 5
// 190.475 us; speedup vs baseline: 3.7935x; 3.7935x over previous
//
#include <hip/hip_runtime.h>
#include <hip/hip_bf16.h>
#include <math.h>

#define BB 16
#define IC 64
#define CH 128
#define LL 16384
#define KS 5
#define CAK 5
#define KCR 76
#define EPSV 1e-5f
#define NLT2 256          // psum/pmax partials per (b,c): 128 l-tiles x 2 half-waves

typedef short bf16x8 __attribute__((ext_vector_type(8)));
typedef float f32x16 __attribute__((ext_vector_type(16)));

// ---- workspace layout (in floats) ----
#define OFF_WPACK 0                          // 81920 ushort = 40960 floats
#define OFF_BIAS2 40960                      // 128
#define OFF_PSUM  (OFF_BIAS2 + CH)           // 16*128*256 = 524288
#define OFF_PMAX  (OFF_PSUM + BB*CH*NLT2)
#define OFF_CM    (OFF_PMAX + BB*CH*NLT2)    // 2048
#define OFF_MASK  (OFF_CM + BB*CH)
#define OFF_A1    (OFF_MASK + BB*CH)         // 262144
#define OFF_A2    (OFF_A1 + BB*LL)

__device__ __forceinline__ unsigned short f2bf(float f) {
    union { float f; unsigned u; } v; v.f = f;
    return (unsigned short)((v.u + 0x7FFFu + ((v.u >> 16) & 1u)) >> 16);
}
__device__ __forceinline__ float bf2f(unsigned short h) {
    union { unsigned u; float f; } v; v.u = ((unsigned)h) << 16;
    return v.f;
}

// ---------------------------------------------------------------------------
// Prep: fold BN scale into conv weights, split into bf16 hi/lo, pack in exact
// per-lane MFMA A-fragment order:
//   wpack[((((ver*2+ch2)*2+mt)*20+s)*64+ln)*8+j]
//     c = ch2*64 + mt*32 + (ln&31); kk = s>>2; i = (s&3)*16 + (ln>>5)*8 + j
// ---------------------------------------------------------------------------
__global__ void prep_kernel(const float* __restrict__ conv_w, const float* __restrict__ conv_b,
                            const float* __restrict__ bn_g, const float* __restrict__ bn_b,
                            const float* __restrict__ bn_m, const float* __restrict__ bn_v,
                            unsigned short* __restrict__ wpack, float* __restrict__ bias2)
{
    int e = blockIdx.x * 256 + threadIdx.x;
    if (e < 8 * 20 * 64 * 8) {
        int j    = e & 7;
        int ln   = (e >> 3) & 63;
        int rest = e >> 9;              // 0..159
        int s    = rest % 20;
        int mt   = (rest / 20) & 1;
        int ch2  = (rest / 40) & 1;
        int ver  = rest / 80;
        int c  = ch2 * 64 + mt * 32 + (ln & 31);
        int kk = s >> 2;
        int i  = (s & 3) * 16 + (ln >> 5) * 8 + j;
        float inv = bn_g[c] * rsqrtf(bn_v[c] + EPSV);
        float w = conv_w[(c * IC + i) * KS + kk] * inv;
        unsigned short h = f2bf(w);
        wpack[e] = (ver == 0) ? h : f2bf(w - bf2f(h));
    }
    if (e < CH) {
        float inv = bn_g[e] * rsqrtf(bn_v[e] + EPSV);
        bias2[e] = (conv_b[e] - bn_m[e]) * inv + bn_b[e];
    }
}

// ---------------------------------------------------------------------------
// Split-bf16 MFMA conv + BN + ReLU -> f (fp32, into d_out) + per-channel
// partial sum/max. Block = 128c x 128l, 4 waves of (64c x 64l).
// LDS tile xs[136 rows(l)][128] = [64 hi bf16 | 64 lo bf16], 16B chunks
// XOR-swizzled by (row&7). Main loop: 3-deep A prefetch (global, L2-hot),
// 2-deep B prefetch (LDS), MFMAs interleaved across the 4 accumulators so
// same-acc dependency distance is 4.
// f = wh*xh + wh*xl + wl*xh  (fp32 MFMA accumulate).
// ---------------------------------------------------------------------------
__global__ __launch_bounds__(256, 3)
void conv_mfma_kernel(const float* __restrict__ x,
                      const unsigned short* __restrict__ wpack,
                      const float* __restrict__ bias2,
                      float* __restrict__ f,
                      float* __restrict__ psum, float* __restrict__ pmax)
{
    __shared__ unsigned short xs[136 * 128];   // 34,816 B
    const int b   = blockIdx.x;
    const int lt  = blockIdx.y;
    const int l0  = lt * 128;
    const int tid = threadIdx.x;
    const int ln  = tid & 63;
    const int wv  = __builtin_amdgcn_readfirstlane(tid >> 6);

    // ---- staging: wave wv owns i in [wv*16, wv*16+16); lane = row (l) ----
    const float* xb = x + (size_t)b * (IC * LL);
    const int ibase = wv * 16;
    #pragma unroll
    for (int g = 0; g < 3; ++g) {
        int row = g * 64 + ln;           // 0..191; valid rows < 136
        int l   = l0 - 4 + row;
        if (row < 136) {
            bool vl = (l >= 0) && (l < LL);
            float v[16];
            #pragma unroll
            for (int q = 0; q < 16; ++q)
                v[q] = vl ? xb[(size_t)(ibase + q) * LL + l] : 0.0f;
            int rs = row & 7;
            #pragma unroll
            for (int q2 = 0; q2 < 4; ++q2) {
                unsigned short h[4], lo[4];
                #pragma unroll
                for (int j = 0; j < 4; ++j) {
                    float vv = v[q2 * 4 + j];
                    h[j]  = f2bf(vv);
                    lo[j] = f2bf(vv - bf2f(h[j]));
                }
                int i0   = ibase + q2 * 4;
                int cc   = (i0 >> 3) ^ rs;
                int epos = row * 128 + cc * 8 + (i0 & 7);
                uint2 wh, wl;
                wh.x = (unsigned)h[0]  | ((unsigned)h[1]  << 16);
                wh.y = (unsigned)h[2]  | ((unsigned)h[3]  << 16);
                wl.x = (unsigned)lo[0] | ((unsigned)lo[1] << 16);
                wl.y = (unsigned)lo[2] | ((unsigned)lo[3] << 16);
                *(uint2*)&xs[epos]      = wh;
                *(uint2*)&xs[epos + 64] = wl;
            }
        }
    }
    __syncthreads();

    const int ch2  = wv >> 1;   // c-half: 0 -> c 0..63, 1 -> 64..127
    const int lh   = wv & 1;    // l-half within the 128-l tile
    const int ln31 = ln & 31;
    const int hi   = ln >> 5;
    const int rowbase = lh * 64 + ln31 + 2;

    // A-fragment stream pointers (wpack is L2-hot, 160 KB)
    const unsigned short* wp  = wpack + (size_t)ln * 8;
    const unsigned short* pA0 = wp + (size_t)((ch2 * 2 + 0) * 20) * 512;       // wh, mt0
    const unsigned short* pA1 = wp + (size_t)((ch2 * 2 + 1) * 20) * 512;       // wh, mt1
    const unsigned short* pA2 = wp + (size_t)(((2 + ch2) * 2 + 0) * 20) * 512; // wl, mt0
    const unsigned short* pA3 = wp + (size_t)(((2 + ch2) * 2 + 1) * 20) * 512; // wl, mt1

    f32x16 acc[2][2];
    #pragma unroll
    for (int mt = 0; mt < 2; ++mt)
        #pragma unroll
        for (int nt = 0; nt < 2; ++nt)
            #pragma unroll
            for (int r = 0; r < 16; ++r) acc[mt][nt][r] = 0.0f;

    auto loadA = [&](bf16x8* Av, int s) {
        Av[0] = *(const bf16x8*)(pA0 + (size_t)s * 512);
        Av[1] = *(const bf16x8*)(pA1 + (size_t)s * 512);
        Av[2] = *(const bf16x8*)(pA2 + (size_t)s * 512);
        Av[3] = *(const bf16x8*)(pA3 + (size_t)s * 512);
    };
    auto loadB = [&](bf16x8* Bv, int s) {
        int kk = s >> 2, iq = s & 3;
        int r0 = rowbase + kk;
        int r1 = r0 + 32;
        int c0 = ((iq << 1) + hi) ^ (r0 & 7);
        int c1 = ((iq << 1) + hi) ^ (r1 & 7);
        Bv[0] = *(const bf16x8*)&xs[r0 * 128 + c0 * 8];        // bh, nt0
        Bv[1] = *(const bf16x8*)&xs[r0 * 128 + 64 + c0 * 8];   // bl, nt0
        Bv[2] = *(const bf16x8*)&xs[r1 * 128 + c1 * 8];        // bh, nt1
        Bv[3] = *(const bf16x8*)&xs[r1 * 128 + 64 + c1 * 8];   // bl, nt1
    };
    // Interleaved across the 4 accumulators: same-acc dep distance = 4.
    auto compute = [&](const bf16x8* Av, const bf16x8* Bv) {
        acc[0][0] = __builtin_amdgcn_mfma_f32_32x32x16_bf16(Av[0], Bv[0], acc[0][0], 0, 0, 0);
        acc[1][0] = __builtin_amdgcn_mfma_f32_32x32x16_bf16(Av[1], Bv[0], acc[1][0], 0, 0, 0);
        acc[0][1] = __builtin_amdgcn_mfma_f32_32x32x16_bf16(Av[0], Bv[2], acc[0][1], 0, 0, 0);
        acc[1][1] = __builtin_amdgcn_mfma_f32_32x32x16_bf16(Av[1], Bv[2], acc[1][1], 0, 0, 0);
        acc[0][0] = __builtin_amdgcn_mfma_f32_32x32x16_bf16(Av[0], Bv[1], acc[0][0], 0, 0, 0);
        acc[1][0] = __builtin_amdgcn_mfma_f32_32x32x16_bf16(Av[1], Bv[1], acc[1][0], 0, 0, 0);
        acc[0][1] = __builtin_amdgcn_mfma_f32_32x32x16_bf16(Av[0], Bv[3], acc[0][1], 0, 0, 0);
        acc[1][1] = __builtin_amdgcn_mfma_f32_32x32x16_bf16(Av[1], Bv[3], acc[1][1], 0, 0, 0);
        acc[0][0] = __builtin_amdgcn_mfma_f32_32x32x16_bf16(Av[2], Bv[0], acc[0][0], 0, 0, 0);
        acc[1][0] = __builtin_amdgcn_mfma_f32_32x32x16_bf16(Av[3], Bv[0], acc[1][0], 0, 0, 0);
        acc[0][1] = __builtin_amdgcn_mfma_f32_32x32x16_bf16(Av[2], Bv[2], acc[0][1], 0, 0, 0);
        acc[1][1] = __builtin_amdgcn_mfma_f32_32x32x16_bf16(Av[3], Bv[2], acc[1][1], 0, 0, 0);
    };

    // ---- main loop: 3-deep A ring, 2-deep B ring ----
    bf16x8 Ar[3][4], Br[2][4];
    loadA(Ar[0], 0); loadA(Ar[1], 1); loadA(Ar[2], 2);
    loadB(Br[0], 0); loadB(Br[1], 1);
    #pragma unroll
    for (int s = 0; s < 20; ++s) {
        compute(Ar[s % 3], Br[s & 1]);
        if (s + 3 < 20) loadA(Ar[s % 3], s + 3);
        if (s + 2 < 20) loadB(Br[s & 1], s + 2);
    }

    // ---- epilogue: bias + relu, store f, per-channel partial sum/max ----
    // D mapping (32x32): col(l) = ln&31, row(c) = (r&3) + 8*(r>>2) + 4*(ln>>5)
    const int lgbase = l0 + lh * 64 + ln31;
    #pragma unroll
    for (int mt = 0; mt < 2; ++mt) {
        #pragma unroll
        for (int nt = 0; nt < 2; ++nt) {
            #pragma unroll
            for (int r = 0; r < 16; ++r) {
                int c = ch2 * 64 + mt * 32 + (r & 3) + 8 * (r >> 2) + 4 * hi;
                float fv = fmaxf(acc[mt][nt][r] + bias2[c], 0.0f);
                f[((size_t)(b * CH + c)) * LL + lgbase + nt * 32] = fv;
                acc[mt][nt][r] = fv;
            }
        }
    }
    #pragma unroll
    for (int mt = 0; mt < 2; ++mt) {
        #pragma unroll
        for (int r = 0; r < 16; ++r) {
            float s = acc[mt][0][r] + acc[mt][1][r];
            float m = fmaxf(acc[mt][0][r], acc[mt][1][r]);
            #pragma unroll
            for (int off = 1; off <= 16; off <<= 1) {
                s += __shfl_xor(s, off, 64);
                m = fmaxf(m, __shfl_xor(m, off, 64));
            }
            if (ln31 == 0) {
                int c   = ch2 * 64 + mt * 32 + (r & 3) + 8 * (r >> 2) + 4 * hi;
                int lt2 = lt * 2 + lh;
                psum[(b * CH + c) * NLT2 + lt2] = s;
                pmax[(b * CH + c) * NLT2 + lt2] = m;
            }
        }
    }
}

// ---------------------------------------------------------------------------
// Per-batch: finish L-reductions, channel attention, top-K mask (rank count,
// ties by lower index to match jax.lax.top_k). Grid: B x 128 threads.
// ---------------------------------------------------------------------------
__global__ void chan_kernel(const float* __restrict__ psum, const float* __restrict__ pmax,
                            const float* __restrict__ alpha, const float* __restrict__ beta,
                            const float* __restrict__ ca_w, const float* __restrict__ ca_b,
                            float* __restrict__ cm, float* __restrict__ maskv)
{
    int b = blockIdx.x;
    int c = threadIdx.x;   // 128
    const float* ps = psum + (b * CH + c) * NLT2;
    const float* pm = pmax + (b * CH + c) * NLT2;
    float s = 0.0f, m = 0.0f;
    for (int t = 0; t < NLT2; ++t) { s += ps[t]; m = fmaxf(m, pm[t]); }
    float favg = s * (1.0f / LL);
    float fadd = (alpha[0] + 0.5f) * favg + (beta[0] + 0.5f) * m;

    __shared__ float fa[CH];
    __shared__ float cms[CH];
    fa[c] = fadd;
    __syncthreads();

    float z = ca_b[0];
    #pragma unroll
    for (int k = 0; k < CAK; ++k) {
        int cc = c + k - 2;
        float v = (cc >= 0 && cc < CH) ? fa[cc] : 0.0f;
        z = fmaf(ca_w[k], v, z);
    }
    float cmv = 1.0f / (1.0f + expf(-z));
    cms[c] = cmv;
    __syncthreads();

    int rank = 0;
    for (int cc = 0; cc < CH; ++cc) {
        float o = cms[cc];
        rank += (o > cmv || (o == cmv && cc < c)) ? 1 : 0;
    }
    cm[b * CH + c] = cmv;
    maskv[b * CH + c] = (rank < KCR) ? 1.0f : 0.0f;
}

// ---------------------------------------------------------------------------
// Fused stats + gate: per (b,l) cross-channel group stats of crf = f*cm, with
// +/-3 halo recomputed locally (f untouched), then the 7-tap gate conv + BN +
// ReLU + sigmoid -> A1, A2. Grid (B, 64) x 256.
// ---------------------------------------------------------------------------
__global__ __launch_bounds__(256)
void stats_gate_kernel(const float* __restrict__ f, const float* __restrict__ cm,
                       const float* __restrict__ maskv, const float* __restrict__ sa_w,
                       const float* __restrict__ sabn_g, const float* __restrict__ sabn_b,
                       const float* __restrict__ sabn_m, const float* __restrict__ sabn_v,
                       float* __restrict__ A1, float* __restrict__ A2)
{
    __shared__ float cms[CH], mks[CH];
    __shared__ float st[4][264];
    int b   = blockIdx.x;
    int l0  = blockIdx.y * 256;
    int tid = threadIdx.x;
    if (tid < CH) { cms[tid] = cm[b * CH + tid]; mks[tid] = maskv[b * CH + tid]; }
    __syncthreads();

    for (int idx = tid; idx < 262; idx += 256) {
        int l = l0 - 3 + idx;
        float cmx = 0.f, csm = 0.f, smx = 0.f, ssm = 0.f;
        if (l >= 0 && l < LL) {
            const float* fb = f + (size_t)b * CH * LL + l;
            #pragma unroll 4
            for (int c = 0; c < CH; ++c) {
                float v  = fb[(size_t)c * LL] * cms[c];
                float mk = mks[c];
                float vs = v * mk;
                float vu = v - vs;
                cmx = fmaxf(cmx, vs);
                smx = fmaxf(smx, vu);
                csm += vs;
                ssm += vu;
            }
        }
        st[0][idx] = cmx;
        st[1][idx] = csm * (1.0f / KCR);
        st[2][idx] = smx;
        st[3][idx] = ssm * (1.0f / (CH - KCR));
    }
    __syncthreads();

    float inv = sabn_g[0] * rsqrtf(sabn_v[0] + EPSV);
    float bb2 = sabn_b[0] - sabn_m[0] * inv;
    float y1 = 0.f, y2 = 0.f;
    #pragma unroll
    for (int k = 0; k < 7; ++k) {
        float wm = sa_w[k], wa = sa_w[7 + k];
        y1 = fmaf(wm, st[0][tid + k], fmaf(wa, st[1][tid + k], y1));
        y2 = fmaf(wm, st[2][tid + k], fmaf(wa, st[3][tid + k], y2));
    }
    float t1 = fmaxf(y1 * inv + bb2, 0.f);
    float t2 = fmaxf(y2 * inv + bb2, 0.f);
    A1[b * LL + l0 + tid] = 1.0f / (1.0f + expf(-t1));
    A2[b * LL + l0 + tid] = 1.0f / (1.0f + expf(-t2));
}

// ---------------------------------------------------------------------------
// Final: out = f * cm[b,c] * (mask ? A1 : A2), in place on d_out.
// ---------------------------------------------------------------------------
__global__ __launch_bounds__(256)
void final_kernel(float* __restrict__ out, const float* __restrict__ cm,
                  const float* __restrict__ maskv,
                  const float* __restrict__ A1, const float* __restrict__ A2)
{
    int g = blockIdx.x * 256 + threadIdx.x;
    size_t idx4 = (size_t)g * 4;
    int l  = (int)(idx4 & (LL - 1));
    int bc = (int)(idx4 >> 14);
    int b  = bc >> 7;
    float cmv = cm[bc];
    float mk  = maskv[bc];
    const float* Ap = (mk > 0.5f) ? A1 : A2;
    float4 a = *(const float4*)&Ap[b * LL + l];
    float4 v = *(const float4*)&out[idx4];
    v.x *= cmv * a.x;
    v.y *= cmv * a.y;
    v.z *= cmv * a.z;
    v.w *= cmv * a.w;
    *(float4*)&out[idx4] = v;
}

extern "C" void kernel_launch(void* const* d_in, const int* in_sizes, int n_in,
                              void* d_out, int out_size, void* d_ws, size_t ws_size,
                              hipStream_t stream)
{
    const float* x      = (const float*)d_in[0];
    const float* conv_w = (const float*)d_in[1];
    const float* conv_b = (const float*)d_in[2];
    const float* bn_g   = (const float*)d_in[3];
    const float* bn_b   = (const float*)d_in[4];
    const float* bn_m   = (const float*)d_in[5];
    const float* bn_v   = (const float*)d_in[6];
    const float* alpha  = (const float*)d_in[7];
    const float* beta   = (const float*)d_in[8];
    const float* ca_w   = (const float*)d_in[9];
    const float* ca_b   = (const float*)d_in[10];
    const float* sa_w   = (const float*)d_in[11];
    const float* sabn_g = (const float*)d_in[12];
    const float* sabn_b = (const float*)d_in[13];
    const float* sabn_m = (const float*)d_in[14];
    const float* sabn_v = (const float*)d_in[15];

    float* out = (float*)d_out;
    float* ws  = (float*)d_ws;

    unsigned short* wpack = (unsigned short*)(ws + OFF_WPACK);
    float* bias2 = ws + OFF_BIAS2;
    float* psum  = ws + OFF_PSUM;
    float* pmax  = ws + OFF_PMAX;
    float* cmv_  = ws + OFF_CM;
    float* mskv  = ws + OFF_MASK;
    float* A1p   = ws + OFF_A1;
    float* A2p   = ws + OFF_A2;

    prep_kernel<<<320, 256, 0, stream>>>(conv_w, conv_b, bn_g, bn_b, bn_m, bn_v, wpack, bias2);

    conv_mfma_kernel<<<dim3(BB, 128), 256, 0, stream>>>(x, wpack, bias2, out, psum, pmax);

    chan_kernel<<<BB, CH, 0, stream>>>(psum, pmax, alpha, beta, ca_w, ca_b, cmv_, mskv);

    stats_gate_kernel<<<dim3(BB, 64), 256, 0, stream>>>(out, cmv_, mskv, sa_w,
                                                        sabn_g, sabn_b, sabn_m, sabn_v, A1p, A2p);

    final_kernel<<<(BB * CH * LL / 4 + 255) / 256, 256, 0, stream>>>(out, cmv_, mskv, A1p, A2p);
}

// Round 6
// 177.471 us; speedup vs baseline: 4.0715x; 1.0733x over previous
//
#include <hip/hip_runtime.h>
#include <hip/hip_bf16.h>
#include <math.h>

#define BB 16
#define IC 64
#define CH 128
#define LL 16384
#define KS 5
#define CAK 5
#define KCR 76
#define EPSV 1e-5f
#define NLT2 256          // psum/pmax partials per (b,c): 128 l-tiles x 2 half-waves

typedef short bf16x8 __attribute__((ext_vector_type(8)));
typedef float f32x16 __attribute__((ext_vector_type(16)));

// ---- workspace layout (in floats) ----
#define OFF_WPACK 0                          // 81920 ushort = 40960 floats
#define OFF_BIAS2 40960                      // 128
#define OFF_PSUM  (OFF_BIAS2 + CH)           // 16*128*256 = 524288
#define OFF_PMAX  (OFF_PSUM + BB*CH*NLT2)
#define OFF_CM    (OFF_PMAX + BB*CH*NLT2)    // 2048
#define OFF_MASK  (OFF_CM + BB*CH)
#define OFF_A1    (OFF_MASK + BB*CH)         // 262144
#define OFF_A2    (OFF_A1 + BB*LL)

__device__ __forceinline__ unsigned short f2bf(float f) {
    union { float f; unsigned u; } v; v.f = f;
    return (unsigned short)((v.u + 0x7FFFu + ((v.u >> 16) & 1u)) >> 16);
}
__device__ __forceinline__ float bf2f(unsigned short h) {
    union { unsigned u; float f; } v; v.u = ((unsigned)h) << 16;
    return v.f;
}

// DPP lane-shift (VALU pipe, no LDS). bound_ctrl=true: invalid lanes -> 0.
template<int CTRL>
__device__ __forceinline__ float dppf(float v) {
    return __builtin_bit_cast(float,
        __builtin_amdgcn_update_dpp(0, __builtin_bit_cast(int, v), CTRL, 0xF, 0xF, true));
}
// 32-lane-half reduction: totals land in lanes 31 and 63. f>=0 so zero-fill ok.
__device__ __forceinline__ float dpp_sum32(float s) {
    s += dppf<0x111>(s);   // row_shr:1
    s += dppf<0x112>(s);   // row_shr:2
    s += dppf<0x114>(s);   // row_shr:4
    s += dppf<0x118>(s);   // row_shr:8
    s += dppf<0x142>(s);   // row_bcast:15
    return s;
}
__device__ __forceinline__ float dpp_max32(float m) {
    m = fmaxf(m, dppf<0x111>(m));
    m = fmaxf(m, dppf<0x112>(m));
    m = fmaxf(m, dppf<0x114>(m));
    m = fmaxf(m, dppf<0x118>(m));
    m = fmaxf(m, dppf<0x142>(m));
    return m;
}

// ---------------------------------------------------------------------------
// Prep: fold BN scale into conv weights, split into bf16 hi/lo, pack in exact
// per-lane MFMA A-fragment order:
//   wpack[((((ver*2+ch2)*2+mt)*20+s)*64+ln)*8+j]
//     c = ch2*64 + mt*32 + (ln&31); kk = s>>2; i = (s&3)*16 + (ln>>5)*8 + j
// ---------------------------------------------------------------------------
__global__ void prep_kernel(const float* __restrict__ conv_w, const float* __restrict__ conv_b,
                            const float* __restrict__ bn_g, const float* __restrict__ bn_b,
                            const float* __restrict__ bn_m, const float* __restrict__ bn_v,
                            unsigned short* __restrict__ wpack, float* __restrict__ bias2)
{
    int e = blockIdx.x * 256 + threadIdx.x;
    if (e < 8 * 20 * 64 * 8) {
        int j    = e & 7;
        int ln   = (e >> 3) & 63;
        int rest = e >> 9;              // 0..159
        int s    = rest % 20;
        int mt   = (rest / 20) & 1;
        int ch2  = (rest / 40) & 1;
        int ver  = rest / 80;
        int c  = ch2 * 64 + mt * 32 + (ln & 31);
        int kk = s >> 2;
        int i  = (s & 3) * 16 + (ln >> 5) * 8 + j;
        float inv = bn_g[c] * rsqrtf(bn_v[c] + EPSV);
        float w = conv_w[(c * IC + i) * KS + kk] * inv;
        unsigned short h = f2bf(w);
        wpack[e] = (ver == 0) ? h : f2bf(w - bf2f(h));
    }
    if (e < CH) {
        float inv = bn_g[e] * rsqrtf(bn_v[e] + EPSV);
        bias2[e] = (conv_b[e] - bn_m[e]) * inv + bn_b[e];
    }
}

// ---------------------------------------------------------------------------
// Split-bf16 MFMA conv + BN + ReLU -> f (fp32, into d_out) + per-channel
// partial sum/max. Block = 128c x 128l, 4 waves of (64c x 64l).
// LDS tile xs[136 rows(l)][128] = [64 hi bf16 | 64 lo bf16], 16B chunks
// XOR-swizzled by (row&7). Epilogue reduction via DPP (VALU, no LDS).
// f = wh*xh + wh*xl + wl*xh  (fp32 MFMA accumulate).
// ---------------------------------------------------------------------------
__global__ __launch_bounds__(256, 4)
void conv_mfma_kernel(const float* __restrict__ x,
                      const unsigned short* __restrict__ wpack,
                      const float* __restrict__ bias2,
                      float* __restrict__ f,
                      float* __restrict__ psum, float* __restrict__ pmax)
{
    __shared__ unsigned short xs[136 * 128];   // 34,816 B -> 4 blocks/CU
    const int b   = blockIdx.x;
    const int lt  = blockIdx.y;
    const int l0  = lt * 128;
    const int tid = threadIdx.x;
    const int ln  = tid & 63;
    const int wv  = __builtin_amdgcn_readfirstlane(tid >> 6);

    // ---- staging: wave wv owns i in [wv*16, wv*16+16); lane = row (l) ----
    const float* xb = x + (size_t)b * (IC * LL);
    const int ibase = wv * 16;
    #pragma unroll
    for (int g = 0; g < 3; ++g) {
        int row = g * 64 + ln;           // 0..191; valid rows < 136
        int l   = l0 - 4 + row;
        if (row < 136) {
            bool vl = (l >= 0) && (l < LL);
            float v[16];
            #pragma unroll
            for (int q = 0; q < 16; ++q)
                v[q] = vl ? xb[(size_t)(ibase + q) * LL + l] : 0.0f;
            int rs = row & 7;
            #pragma unroll
            for (int q2 = 0; q2 < 4; ++q2) {
                unsigned short h[4], lo[4];
                #pragma unroll
                for (int j = 0; j < 4; ++j) {
                    float vv = v[q2 * 4 + j];
                    h[j]  = f2bf(vv);
                    lo[j] = f2bf(vv - bf2f(h[j]));
                }
                int i0   = ibase + q2 * 4;
                int cc   = (i0 >> 3) ^ rs;
                int epos = row * 128 + cc * 8 + (i0 & 7);
                uint2 wh, wl;
                wh.x = (unsigned)h[0]  | ((unsigned)h[1]  << 16);
                wh.y = (unsigned)h[2]  | ((unsigned)h[3]  << 16);
                wl.x = (unsigned)lo[0] | ((unsigned)lo[1] << 16);
                wl.y = (unsigned)lo[2] | ((unsigned)lo[3] << 16);
                *(uint2*)&xs[epos]      = wh;
                *(uint2*)&xs[epos + 64] = wl;
            }
        }
    }
    __syncthreads();

    const int ch2  = wv >> 1;   // c-half: 0 -> c 0..63, 1 -> 64..127
    const int lh   = wv & 1;    // l-half within the 128-l tile
    const int ln31 = ln & 31;
    const int hi   = ln >> 5;
    const int rowbase = lh * 64 + ln31 + 2;

    // A-fragment stream pointers (wpack is L2-hot, 160 KB)
    const unsigned short* wp  = wpack + (size_t)ln * 8;
    const unsigned short* pA0 = wp + (size_t)((ch2 * 2 + 0) * 20) * 512;       // wh, mt0
    const unsigned short* pA1 = wp + (size_t)((ch2 * 2 + 1) * 20) * 512;       // wh, mt1
    const unsigned short* pA2 = wp + (size_t)(((2 + ch2) * 2 + 0) * 20) * 512; // wl, mt0
    const unsigned short* pA3 = wp + (size_t)(((2 + ch2) * 2 + 1) * 20) * 512; // wl, mt1

    f32x16 acc[2][2];
    #pragma unroll
    for (int mt = 0; mt < 2; ++mt)
        #pragma unroll
        for (int nt = 0; nt < 2; ++nt)
            #pragma unroll
            for (int r = 0; r < 16; ++r) acc[mt][nt][r] = 0.0f;

    auto loadA = [&](bf16x8* Av, int s) {
        Av[0] = *(const bf16x8*)(pA0 + (size_t)s * 512);
        Av[1] = *(const bf16x8*)(pA1 + (size_t)s * 512);
        Av[2] = *(const bf16x8*)(pA2 + (size_t)s * 512);
        Av[3] = *(const bf16x8*)(pA3 + (size_t)s * 512);
    };
    auto loadB = [&](bf16x8* Bv, int s) {
        int kk = s >> 2, iq = s & 3;
        int r0 = rowbase + kk;
        int r1 = r0 + 32;
        int c0 = ((iq << 1) + hi) ^ (r0 & 7);
        int c1 = ((iq << 1) + hi) ^ (r1 & 7);
        Bv[0] = *(const bf16x8*)&xs[r0 * 128 + c0 * 8];        // bh, nt0
        Bv[1] = *(const bf16x8*)&xs[r0 * 128 + 64 + c0 * 8];   // bl, nt0
        Bv[2] = *(const bf16x8*)&xs[r1 * 128 + c1 * 8];        // bh, nt1
        Bv[3] = *(const bf16x8*)&xs[r1 * 128 + 64 + c1 * 8];   // bl, nt1
    };
    // Interleaved across the 4 accumulators: same-acc dep distance = 4.
    auto compute = [&](const bf16x8* Av, const bf16x8* Bv) {
        acc[0][0] = __builtin_amdgcn_mfma_f32_32x32x16_bf16(Av[0], Bv[0], acc[0][0], 0, 0, 0);
        acc[1][0] = __builtin_amdgcn_mfma_f32_32x32x16_bf16(Av[1], Bv[0], acc[1][0], 0, 0, 0);
        acc[0][1] = __builtin_amdgcn_mfma_f32_32x32x16_bf16(Av[0], Bv[2], acc[0][1], 0, 0, 0);
        acc[1][1] = __builtin_amdgcn_mfma_f32_32x32x16_bf16(Av[1], Bv[2], acc[1][1], 0, 0, 0);
        acc[0][0] = __builtin_amdgcn_mfma_f32_32x32x16_bf16(Av[0], Bv[1], acc[0][0], 0, 0, 0);
        acc[1][0] = __builtin_amdgcn_mfma_f32_32x32x16_bf16(Av[1], Bv[1], acc[1][0], 0, 0, 0);
        acc[0][1] = __builtin_amdgcn_mfma_f32_32x32x16_bf16(Av[0], Bv[3], acc[0][1], 0, 0, 0);
        acc[1][1] = __builtin_amdgcn_mfma_f32_32x32x16_bf16(Av[1], Bv[3], acc[1][1], 0, 0, 0);
        acc[0][0] = __builtin_amdgcn_mfma_f32_32x32x16_bf16(Av[2], Bv[0], acc[0][0], 0, 0, 0);
        acc[1][0] = __builtin_amdgcn_mfma_f32_32x32x16_bf16(Av[3], Bv[0], acc[1][0], 0, 0, 0);
        acc[0][1] = __builtin_amdgcn_mfma_f32_32x32x16_bf16(Av[2], Bv[2], acc[0][1], 0, 0, 0);
        acc[1][1] = __builtin_amdgcn_mfma_f32_32x32x16_bf16(Av[3], Bv[2], acc[1][1], 0, 0, 0);
    };

    // ---- main loop: 3-deep A ring, 2-deep B ring ----
    bf16x8 Ar[3][4], Br[2][4];
    loadA(Ar[0], 0); loadA(Ar[1], 1); loadA(Ar[2], 2);
    loadB(Br[0], 0); loadB(Br[1], 1);
    #pragma unroll
    for (int s = 0; s < 20; ++s) {
        compute(Ar[s % 3], Br[s & 1]);
        if (s + 3 < 20) loadA(Ar[s % 3], s + 3);
        if (s + 2 < 20) loadB(Br[s & 1], s + 2);
    }

    // ---- epilogue: bias + relu, store f, per-channel partial sum/max ----
    // D mapping (32x32): col(l) = ln&31, row(c) = (r&3) + 8*(r>>2) + 4*(ln>>5)
    const int lgbase = l0 + lh * 64 + ln31;
    #pragma unroll
    for (int mt = 0; mt < 2; ++mt) {
        #pragma unroll
        for (int nt = 0; nt < 2; ++nt) {
            #pragma unroll
            for (int r = 0; r < 16; ++r) {
                int c = ch2 * 64 + mt * 32 + (r & 3) + 8 * (r >> 2) + 4 * hi;
                float fv = fmaxf(acc[mt][nt][r] + bias2[c], 0.0f);
                f[((size_t)(b * CH + c)) * LL + lgbase + nt * 32] = fv;
                acc[mt][nt][r] = fv;
            }
        }
    }
    // per-channel partial sum/max over this wave's 64 l's, via DPP (no LDS).
    // Totals land in lanes 31 (hi=0 c's) and 63 (hi=1 c's).
    #pragma unroll
    for (int mt = 0; mt < 2; ++mt) {
        #pragma unroll
        for (int r = 0; r < 16; ++r) {
            float s = dpp_sum32(acc[mt][0][r] + acc[mt][1][r]);
            float m = dpp_max32(fmaxf(acc[mt][0][r], acc[mt][1][r]));
            if (ln31 == 31) {
                int c   = ch2 * 64 + mt * 32 + (r & 3) + 8 * (r >> 2) + 4 * hi;
                int lt2 = lt * 2 + lh;
                psum[(b * CH + c) * NLT2 + lt2] = s;
                pmax[(b * CH + c) * NLT2 + lt2] = m;
            }
        }
    }
}

// ---------------------------------------------------------------------------
// Per-batch: finish L-reductions, channel attention, top-K mask (rank count,
// ties by lower index to match jax.lax.top_k). Grid: B x 128 threads.
// ---------------------------------------------------------------------------
__global__ void chan_kernel(const float* __restrict__ psum, const float* __restrict__ pmax,
                            const float* __restrict__ alpha, const float* __restrict__ beta,
                            const float* __restrict__ ca_w, const float* __restrict__ ca_b,
                            float* __restrict__ cm, float* __restrict__ maskv)
{
    int b = blockIdx.x;
    int c = threadIdx.x;   // 128
    const float* ps = psum + (b * CH + c) * NLT2;
    const float* pm = pmax + (b * CH + c) * NLT2;
    float s = 0.0f, m = 0.0f;
    for (int t = 0; t < NLT2; ++t) { s += ps[t]; m = fmaxf(m, pm[t]); }
    float favg = s * (1.0f / LL);
    float fadd = (alpha[0] + 0.5f) * favg + (beta[0] + 0.5f) * m;

    __shared__ float fa[CH];
    __shared__ float cms[CH];
    fa[c] = fadd;
    __syncthreads();

    float z = ca_b[0];
    #pragma unroll
    for (int k = 0; k < CAK; ++k) {
        int cc = c + k - 2;
        float v = (cc >= 0 && cc < CH) ? fa[cc] : 0.0f;
        z = fmaf(ca_w[k], v, z);
    }
    float cmv = 1.0f / (1.0f + expf(-z));
    cms[c] = cmv;
    __syncthreads();

    int rank = 0;
    for (int cc = 0; cc < CH; ++cc) {
        float o = cms[cc];
        rank += (o > cmv || (o == cmv && cc < c)) ? 1 : 0;
    }
    cm[b * CH + c] = cmv;
    maskv[b * CH + c] = (rank < KCR) ? 1.0f : 0.0f;
}

// ---------------------------------------------------------------------------
// Fused stats + gate: per (b,l) cross-channel group stats of crf = f*cm, with
// +/-3 halo recomputed locally (f untouched), then the 7-tap gate conv + BN +
// ReLU + sigmoid -> A1, A2. Grid (B, 64) x 256.
// ---------------------------------------------------------------------------
__global__ __launch_bounds__(256)
void stats_gate_kernel(const float* __restrict__ f, const float* __restrict__ cm,
                       const float* __restrict__ maskv, const float* __restrict__ sa_w,
                       const float* __restrict__ sabn_g, const float* __restrict__ sabn_b,
                       const float* __restrict__ sabn_m, const float* __restrict__ sabn_v,
                       float* __restrict__ A1, float* __restrict__ A2)
{
    __shared__ float cms[CH], mks[CH];
    __shared__ float st[4][264];
    int b   = blockIdx.x;
    int l0  = blockIdx.y * 256;
    int tid = threadIdx.x;
    if (tid < CH) { cms[tid] = cm[b * CH + tid]; mks[tid] = maskv[b * CH + tid]; }
    __syncthreads();

    for (int idx = tid; idx < 262; idx += 256) {
        int l = l0 - 3 + idx;
        float cmx = 0.f, csm = 0.f, smx = 0.f, ssm = 0.f;
        if (l >= 0 && l < LL) {
            const float* fb = f + (size_t)b * CH * LL + l;
            #pragma unroll 4
            for (int c = 0; c < CH; ++c) {
                float v  = fb[(size_t)c * LL] * cms[c];
                float mk = mks[c];
                float vs = v * mk;
                float vu = v - vs;
                cmx = fmaxf(cmx, vs);
                smx = fmaxf(smx, vu);
                csm += vs;
                ssm += vu;
            }
        }
        st[0][idx] = cmx;
        st[1][idx] = csm * (1.0f / KCR);
        st[2][idx] = smx;
        st[3][idx] = ssm * (1.0f / (CH - KCR));
    }
    __syncthreads();

    float inv = sabn_g[0] * rsqrtf(sabn_v[0] + EPSV);
    float bb2 = sabn_b[0] - sabn_m[0] * inv;
    float y1 = 0.f, y2 = 0.f;
    #pragma unroll
    for (int k = 0; k < 7; ++k) {
        float wm = sa_w[k], wa = sa_w[7 + k];
        y1 = fmaf(wm, st[0][tid + k], fmaf(wa, st[1][tid + k], y1));
        y2 = fmaf(wm, st[2][tid + k], fmaf(wa, st[3][tid + k], y2));
    }
    float t1 = fmaxf(y1 * inv + bb2, 0.f);
    float t2 = fmaxf(y2 * inv + bb2, 0.f);
    A1[b * LL + l0 + tid] = 1.0f / (1.0f + expf(-t1));
    A2[b * LL + l0 + tid] = 1.0f / (1.0f + expf(-t2));
}

// ---------------------------------------------------------------------------
// Final: out = f * cm[b,c] * (mask ? A1 : A2), in place on d_out.
// ---------------------------------------------------------------------------
__global__ __launch_bounds__(256)
void final_kernel(float* __restrict__ out, const float* __restrict__ cm,
                  const float* __restrict__ maskv,
                  const float* __restrict__ A1, const float* __restrict__ A2)
{
    int g = blockIdx.x * 256 + threadIdx.x;
    size_t idx4 = (size_t)g * 4;
    int l  = (int)(idx4 & (LL - 1));
    int bc = (int)(idx4 >> 14);
    int b  = bc >> 7;
    float cmv = cm[bc];
    float mk  = maskv[bc];
    const float* Ap = (mk > 0.5f) ? A1 : A2;
    float4 a = *(const float4*)&Ap[b * LL + l];
    float4 v = *(const float4*)&out[idx4];
    v.x *= cmv * a.x;
    v.y *= cmv * a.y;
    v.z *= cmv * a.z;
    v.w *= cmv * a.w;
    *(float4*)&out[idx4] = v;
}

extern "C" void kernel_launch(void* const* d_in, const int* in_sizes, int n_in,
                              void* d_out, int out_size, void* d_ws, size_t ws_size,
                              hipStream_t stream)
{
    const float* x      = (const float*)d_in[0];
    const float* conv_w = (const float*)d_in[1];
    const float* conv_b = (const float*)d_in[2];
    const float* bn_g   = (const float*)d_in[3];
    const float* bn_b   = (const float*)d_in[4];
    const float* bn_m   = (const float*)d_in[5];
    const float* bn_v   = (const float*)d_in[6];
    const float* alpha  = (const float*)d_in[7];
    const float* beta   = (const float*)d_in[8];
    const float* ca_w   = (const float*)d_in[9];
    const float* ca_b   = (const float*)d_in[10];
    const float* sa_w   = (const float*)d_in[11];
    const float* sabn_g = (const float*)d_in[12];
    const float* sabn_b = (const float*)d_in[13];
    const float* sabn_m = (const float*)d_in[14];
    const float* sabn_v = (const float*)d_in[15];

    float* out = (float*)d_out;
    float* ws  = (float*)d_ws;

    unsigned short* wpack = (unsigned short*)(ws + OFF_WPACK);
    float* bias2 = ws + OFF_BIAS2;
    float* psum  = ws + OFF_PSUM;
    float* pmax  = ws + OFF_PMAX;
    float* cmv_  = ws + OFF_CM;
    float* mskv  = ws + OFF_MASK;
    float* A1p   = ws + OFF_A1;
    float* A2p   = ws + OFF_A2;

    prep_kernel<<<320, 256, 0, stream>>>(conv_w, conv_b, bn_g, bn_b, bn_m, bn_v, wpack, bias2);

    conv_mfma_kernel<<<dim3(BB, 128), 256, 0, stream>>>(x, wpack, bias2, out, psum, pmax);

    chan_kernel<<<BB, CH, 0, stream>>>(psum, pmax, alpha, beta, ca_w, ca_b, cmv_, mskv);

    stats_gate_kernel<<<dim3(BB, 64), 256, 0, stream>>>(out, cmv_, mskv, sa_w,
                                                        sabn_g, sabn_b, sabn_m, sabn_v, A1p, A2p);

    final_kernel<<<(BB * CH * LL / 4 + 255) / 256, 256, 0, stream>>>(out, cmv_, mskv, A1p, A2p);
}

// Round 7
// 167.954 us; speedup vs baseline: 4.3022x; 1.0567x over previous
//
#include <hip/hip_runtime.h>
#include <hip/hip_bf16.h>
#include <math.h>

#define BB 16
#define IC 64
#define CH 128
#define LL 16384
#define KS 5
#define CAK 5
#define KCR 76
#define EPSV 1e-5f
#define NLT2 256          // psum/pmax partials per (b,c): 128 l-tiles x 2 half-waves

typedef short bf16x8 __attribute__((ext_vector_type(8)));
typedef float f32x16 __attribute__((ext_vector_type(16)));

// ---- workspace layout (in floats) ----
#define OFF_WPACK 0                          // 81920 ushort = 40960 floats
#define OFF_BIAS2 40960                      // 128
#define OFF_PSUM  (OFF_BIAS2 + CH)           // 16*128*256 = 524288
#define OFF_PMAX  (OFF_PSUM + BB*CH*NLT2)
#define OFF_CM    (OFF_PMAX + BB*CH*NLT2)    // 2048
#define OFF_MASK  (OFF_CM + BB*CH)
#define OFF_A1    (OFF_MASK + BB*CH)         // 262144 (fallback path only)
#define OFF_A2    (OFF_A1 + BB*LL)
#define OFF_F16   (OFF_A2 + BB*LL)           // fp16 f: BB*CH*LL ushorts = 16Mi floats
#define WS_NEED_FLOATS ((size_t)OFF_F16 + (size_t)BB * CH * LL / 2)

__device__ __forceinline__ unsigned short f2bf(float f) {
    union { float f; unsigned u; } v; v.f = f;
    return (unsigned short)((v.u + 0x7FFFu + ((v.u >> 16) & 1u)) >> 16);
}
__device__ __forceinline__ float bf2f(unsigned short h) {
    union { unsigned u; float f; } v; v.u = ((unsigned)h) << 16;
    return v.f;
}
__device__ __forceinline__ unsigned short f2h(float f) {
    _Float16 h = (_Float16)f;
    return __builtin_bit_cast(unsigned short, h);
}
__device__ __forceinline__ float h2f(unsigned short u) {
    _Float16 h = __builtin_bit_cast(_Float16, u);
    return (float)h;
}

// DPP lane-shift (VALU pipe, no LDS). bound_ctrl=true: invalid lanes -> 0.
template<int CTRL>
__device__ __forceinline__ float dppf(float v) {
    return __builtin_bit_cast(float,
        __builtin_amdgcn_update_dpp(0, __builtin_bit_cast(int, v), CTRL, 0xF, 0xF, true));
}
// 32-lane-half reduction: totals land in lanes 31 and 63. f>=0 so zero-fill ok.
__device__ __forceinline__ float dpp_sum32(float s) {
    s += dppf<0x111>(s);   // row_shr:1
    s += dppf<0x112>(s);   // row_shr:2
    s += dppf<0x114>(s);   // row_shr:4
    s += dppf<0x118>(s);   // row_shr:8
    s += dppf<0x142>(s);   // row_bcast:15
    return s;
}
__device__ __forceinline__ float dpp_max32(float m) {
    m = fmaxf(m, dppf<0x111>(m));
    m = fmaxf(m, dppf<0x112>(m));
    m = fmaxf(m, dppf<0x114>(m));
    m = fmaxf(m, dppf<0x118>(m));
    m = fmaxf(m, dppf<0x142>(m));
    return m;
}

// ---------------------------------------------------------------------------
// Prep: fold BN scale into conv weights, split into bf16 hi/lo, pack in exact
// per-lane MFMA A-fragment order:
//   wpack[((((ver*2+ch2)*2+mt)*20+s)*64+ln)*8+j]
//     c = ch2*64 + mt*32 + (ln&31); kk = s>>2; i = (s&3)*16 + (ln>>5)*8 + j
// ---------------------------------------------------------------------------
__global__ void prep_kernel(const float* __restrict__ conv_w, const float* __restrict__ conv_b,
                            const float* __restrict__ bn_g, const float* __restrict__ bn_b,
                            const float* __restrict__ bn_m, const float* __restrict__ bn_v,
                            unsigned short* __restrict__ wpack, float* __restrict__ bias2)
{
    int e = blockIdx.x * 256 + threadIdx.x;
    if (e < 8 * 20 * 64 * 8) {
        int j    = e & 7;
        int ln   = (e >> 3) & 63;
        int rest = e >> 9;              // 0..159
        int s    = rest % 20;
        int mt   = (rest / 20) & 1;
        int ch2  = (rest / 40) & 1;
        int ver  = rest / 80;
        int c  = ch2 * 64 + mt * 32 + (ln & 31);
        int kk = s >> 2;
        int i  = (s & 3) * 16 + (ln >> 5) * 8 + j;
        float inv = bn_g[c] * rsqrtf(bn_v[c] + EPSV);
        float w = conv_w[(c * IC + i) * KS + kk] * inv;
        unsigned short h = f2bf(w);
        wpack[e] = (ver == 0) ? h : f2bf(w - bf2f(h));
    }
    if (e < CH) {
        float inv = bn_g[e] * rsqrtf(bn_v[e] + EPSV);
        bias2[e] = (conv_b[e] - bn_m[e]) * inv + bn_b[e];
    }
}

// ---------------------------------------------------------------------------
// Split-bf16 MFMA conv + BN + ReLU -> f (fp16 into ws, or fp32 into d_out on
// the fallback path) + per-channel partial sum/max (DPP, fp32 pre-quant).
// Block = 128c x 128l, 4 waves of (64c x 64l). LDS tile xs[136][128] =
// [64 hi bf16 | 64 lo bf16], 16B chunks XOR-swizzled by (row&7).
// f = wh*xh + wh*xl + wl*xh  (fp32 MFMA accumulate).
// ---------------------------------------------------------------------------
template<bool F16OUT>
__global__ __launch_bounds__(256, 4)
void conv_mfma_kernel(const float* __restrict__ x,
                      const unsigned short* __restrict__ wpack,
                      const float* __restrict__ bias2,
                      void* __restrict__ fout,
                      float* __restrict__ psum, float* __restrict__ pmax)
{
    __shared__ unsigned short xs[136 * 128];   // 34,816 B -> 4 blocks/CU
    const int b   = blockIdx.x;
    const int lt  = blockIdx.y;
    const int l0  = lt * 128;
    const int tid = threadIdx.x;
    const int ln  = tid & 63;
    const int wv  = __builtin_amdgcn_readfirstlane(tid >> 6);

    // ---- staging: wave wv owns i in [wv*16, wv*16+16); lane = row (l) ----
    const float* xb = x + (size_t)b * (IC * LL);
    const int ibase = wv * 16;
    #pragma unroll
    for (int g = 0; g < 3; ++g) {
        int row = g * 64 + ln;           // 0..191; valid rows < 136
        int l   = l0 - 4 + row;
        if (row < 136) {
            bool vl = (l >= 0) && (l < LL);
            float v[16];
            #pragma unroll
            for (int q = 0; q < 16; ++q)
                v[q] = vl ? xb[(size_t)(ibase + q) * LL + l] : 0.0f;
            int rs = row & 7;
            #pragma unroll
            for (int q2 = 0; q2 < 4; ++q2) {
                unsigned short h[4], lo[4];
                #pragma unroll
                for (int j = 0; j < 4; ++j) {
                    float vv = v[q2 * 4 + j];
                    h[j]  = f2bf(vv);
                    lo[j] = f2bf(vv - bf2f(h[j]));
                }
                int i0   = ibase + q2 * 4;
                int cc   = (i0 >> 3) ^ rs;
                int epos = row * 128 + cc * 8 + (i0 & 7);
                uint2 wh, wl;
                wh.x = (unsigned)h[0]  | ((unsigned)h[1]  << 16);
                wh.y = (unsigned)h[2]  | ((unsigned)h[3]  << 16);
                wl.x = (unsigned)lo[0] | ((unsigned)lo[1] << 16);
                wl.y = (unsigned)lo[2] | ((unsigned)lo[3] << 16);
                *(uint2*)&xs[epos]      = wh;
                *(uint2*)&xs[epos + 64] = wl;
            }
        }
    }
    __syncthreads();

    const int ch2  = wv >> 1;   // c-half: 0 -> c 0..63, 1 -> 64..127
    const int lh   = wv & 1;    // l-half within the 128-l tile
    const int ln31 = ln & 31;
    const int hi   = ln >> 5;
    const int rowbase = lh * 64 + ln31 + 2;

    // A-fragment stream pointers (wpack is L2-hot, 160 KB)
    const unsigned short* wp  = wpack + (size_t)ln * 8;
    const unsigned short* pA0 = wp + (size_t)((ch2 * 2 + 0) * 20) * 512;       // wh, mt0
    const unsigned short* pA1 = wp + (size_t)((ch2 * 2 + 1) * 20) * 512;       // wh, mt1
    const unsigned short* pA2 = wp + (size_t)(((2 + ch2) * 2 + 0) * 20) * 512; // wl, mt0
    const unsigned short* pA3 = wp + (size_t)(((2 + ch2) * 2 + 1) * 20) * 512; // wl, mt1

    f32x16 acc[2][2];
    #pragma unroll
    for (int mt = 0; mt < 2; ++mt)
        #pragma unroll
        for (int nt = 0; nt < 2; ++nt)
            #pragma unroll
            for (int r = 0; r < 16; ++r) acc[mt][nt][r] = 0.0f;

    auto loadA = [&](bf16x8* Av, int s) {
        Av[0] = *(const bf16x8*)(pA0 + (size_t)s * 512);
        Av[1] = *(const bf16x8*)(pA1 + (size_t)s * 512);
        Av[2] = *(const bf16x8*)(pA2 + (size_t)s * 512);
        Av[3] = *(const bf16x8*)(pA3 + (size_t)s * 512);
    };
    auto loadB = [&](bf16x8* Bv, int s) {
        int kk = s >> 2, iq = s & 3;
        int r0 = rowbase + kk;
        int r1 = r0 + 32;
        int c0 = ((iq << 1) + hi) ^ (r0 & 7);
        int c1 = ((iq << 1) + hi) ^ (r1 & 7);
        Bv[0] = *(const bf16x8*)&xs[r0 * 128 + c0 * 8];        // bh, nt0
        Bv[1] = *(const bf16x8*)&xs[r0 * 128 + 64 + c0 * 8];   // bl, nt0
        Bv[2] = *(const bf16x8*)&xs[r1 * 128 + c1 * 8];        // bh, nt1
        Bv[3] = *(const bf16x8*)&xs[r1 * 128 + 64 + c1 * 8];   // bl, nt1
    };
    // Interleaved across the 4 accumulators: same-acc dep distance = 4.
    auto compute = [&](const bf16x8* Av, const bf16x8* Bv) {
        acc[0][0] = __builtin_amdgcn_mfma_f32_32x32x16_bf16(Av[0], Bv[0], acc[0][0], 0, 0, 0);
        acc[1][0] = __builtin_amdgcn_mfma_f32_32x32x16_bf16(Av[1], Bv[0], acc[1][0], 0, 0, 0);
        acc[0][1] = __builtin_amdgcn_mfma_f32_32x32x16_bf16(Av[0], Bv[2], acc[0][1], 0, 0, 0);
        acc[1][1] = __builtin_amdgcn_mfma_f32_32x32x16_bf16(Av[1], Bv[2], acc[1][1], 0, 0, 0);
        acc[0][0] = __builtin_amdgcn_mfma_f32_32x32x16_bf16(Av[0], Bv[1], acc[0][0], 0, 0, 0);
        acc[1][0] = __builtin_amdgcn_mfma_f32_32x32x16_bf16(Av[1], Bv[1], acc[1][0], 0, 0, 0);
        acc[0][1] = __builtin_amdgcn_mfma_f32_32x32x16_bf16(Av[0], Bv[3], acc[0][1], 0, 0, 0);
        acc[1][1] = __builtin_amdgcn_mfma_f32_32x32x16_bf16(Av[1], Bv[3], acc[1][1], 0, 0, 0);
        acc[0][0] = __builtin_amdgcn_mfma_f32_32x32x16_bf16(Av[2], Bv[0], acc[0][0], 0, 0, 0);
        acc[1][0] = __builtin_amdgcn_mfma_f32_32x32x16_bf16(Av[3], Bv[0], acc[1][0], 0, 0, 0);
        acc[0][1] = __builtin_amdgcn_mfma_f32_32x32x16_bf16(Av[2], Bv[2], acc[0][1], 0, 0, 0);
        acc[1][1] = __builtin_amdgcn_mfma_f32_32x32x16_bf16(Av[3], Bv[2], acc[1][1], 0, 0, 0);
    };

    // ---- main loop: 3-deep A ring, 2-deep B ring ----
    bf16x8 Ar[3][4], Br[2][4];
    loadA(Ar[0], 0); loadA(Ar[1], 1); loadA(Ar[2], 2);
    loadB(Br[0], 0); loadB(Br[1], 1);
    #pragma unroll
    for (int s = 0; s < 20; ++s) {
        compute(Ar[s % 3], Br[s & 1]);
        if (s + 3 < 20) loadA(Ar[s % 3], s + 3);
        if (s + 2 < 20) loadB(Br[s & 1], s + 2);
    }

    // ---- epilogue: bias + relu, store f, per-channel partial sum/max ----
    // D mapping (32x32): col(l) = ln&31, row(c) = (r&3) + 8*(r>>2) + 4*(ln>>5)
    const int lgbase = l0 + lh * 64 + ln31;
    #pragma unroll
    for (int mt = 0; mt < 2; ++mt) {
        #pragma unroll
        for (int nt = 0; nt < 2; ++nt) {
            #pragma unroll
            for (int r = 0; r < 16; ++r) {
                int c = ch2 * 64 + mt * 32 + (r & 3) + 8 * (r >> 2) + 4 * hi;
                float fv = fmaxf(acc[mt][nt][r] + bias2[c], 0.0f);
                size_t off = ((size_t)(b * CH + c)) * LL + lgbase + nt * 32;
                if constexpr (F16OUT) ((unsigned short*)fout)[off] = f2h(fv);
                else                  ((float*)fout)[off] = fv;
                acc[mt][nt][r] = fv;
            }
        }
    }
    // per-channel partial sum/max over this wave's 64 l's, via DPP (no LDS).
    // Totals land in lanes 31 (hi=0 c's) and 63 (hi=1 c's).
    #pragma unroll
    for (int mt = 0; mt < 2; ++mt) {
        #pragma unroll
        for (int r = 0; r < 16; ++r) {
            float s = dpp_sum32(acc[mt][0][r] + acc[mt][1][r]);
            float m = dpp_max32(fmaxf(acc[mt][0][r], acc[mt][1][r]));
            if (ln31 == 31) {
                int c   = ch2 * 64 + mt * 32 + (r & 3) + 8 * (r >> 2) + 4 * hi;
                int lt2 = lt * 2 + lh;
                psum[(b * CH + c) * NLT2 + lt2] = s;
                pmax[(b * CH + c) * NLT2 + lt2] = m;
            }
        }
    }
}

// ---------------------------------------------------------------------------
// Per-batch: finish L-reductions, channel attention, top-K mask (rank count,
// ties by lower index to match jax.lax.top_k). Grid: B x 128 threads.
// ---------------------------------------------------------------------------
__global__ void chan_kernel(const float* __restrict__ psum, const float* __restrict__ pmax,
                            const float* __restrict__ alpha, const float* __restrict__ beta,
                            const float* __restrict__ ca_w, const float* __restrict__ ca_b,
                            float* __restrict__ cm, float* __restrict__ maskv)
{
    int b = blockIdx.x;
    int c = threadIdx.x;   // 128
    const float* ps = psum + (b * CH + c) * NLT2;
    const float* pm = pmax + (b * CH + c) * NLT2;
    float s = 0.0f, m = 0.0f;
    for (int t = 0; t < NLT2; ++t) { s += ps[t]; m = fmaxf(m, pm[t]); }
    float favg = s * (1.0f / LL);
    float fadd = (alpha[0] + 0.5f) * favg + (beta[0] + 0.5f) * m;

    __shared__ float fa[CH];
    __shared__ float cms[CH];
    fa[c] = fadd;
    __syncthreads();

    float z = ca_b[0];
    #pragma unroll
    for (int k = 0; k < CAK; ++k) {
        int cc = c + k - 2;
        float v = (cc >= 0 && cc < CH) ? fa[cc] : 0.0f;
        z = fmaf(ca_w[k], v, z);
    }
    float cmv = 1.0f / (1.0f + expf(-z));
    cms[c] = cmv;
    __syncthreads();

    int rank = 0;
    for (int cc = 0; cc < CH; ++cc) {
        float o = cms[cc];
        rank += (o > cmv || (o == cmv && cc < c)) ? 1 : 0;
    }
    cm[b * CH + c] = cmv;
    maskv[b * CH + c] = (rank < KCR) ? 1.0f : 0.0f;
}

// ---------------------------------------------------------------------------
// FP16 path: fused stats + gate + final. Block = (b, 256 l). Phase 1: per-l
// cross-channel group stats of crf = f16*cm (halo read directly from f16 —
// f16 is read-only here, no race). Phase 2: 7-tap gate conv + BN + ReLU +
// sigmoid, then out = f16*cm*(mask?A1:A2) with f16 re-read from L2.
// ---------------------------------------------------------------------------
__global__ __launch_bounds__(256)
void sgf_kernel(const unsigned short* __restrict__ f16, float* __restrict__ out,
                const float* __restrict__ cm, const float* __restrict__ maskv,
                const float* __restrict__ sa_w,
                const float* __restrict__ sabn_g, const float* __restrict__ sabn_b,
                const float* __restrict__ sabn_m, const float* __restrict__ sabn_v)
{
    __shared__ float cms[CH], mks[CH];
    __shared__ float st[4][264];
    const int g   = blockIdx.x;    // 0..63 (256-l tile)
    const int b   = blockIdx.y;
    const int l0  = g * 256;
    const int tid = threadIdx.x;
    if (tid < CH) { cms[tid] = cm[b * CH + tid]; mks[tid] = maskv[b * CH + tid]; }
    __syncthreads();

    for (int idx = tid; idx < 262; idx += 256) {
        int l = l0 - 3 + idx;
        float cmx = 0.f, csm = 0.f, smx = 0.f, ssm = 0.f;
        if (l >= 0 && l < LL) {
            const unsigned short* fb = f16 + (size_t)b * CH * LL + l;
            #pragma unroll 4
            for (int c = 0; c < CH; ++c) {
                float v  = h2f(fb[(size_t)c * LL]) * cms[c];
                float mk = mks[c];
                float vs = v * mk;
                float vu = v - vs;
                cmx = fmaxf(cmx, vs);
                smx = fmaxf(smx, vu);
                csm += vs;
                ssm += vu;
            }
        }
        st[0][idx] = cmx;
        st[1][idx] = csm * (1.0f / KCR);
        st[2][idx] = smx;
        st[3][idx] = ssm * (1.0f / (CH - KCR));
    }
    __syncthreads();

    float inv = sabn_g[0] * rsqrtf(sabn_v[0] + EPSV);
    float bb2 = sabn_b[0] - sabn_m[0] * inv;
    float y1 = 0.f, y2 = 0.f;
    #pragma unroll
    for (int k = 0; k < 7; ++k) {
        float wm = sa_w[k], wa = sa_w[7 + k];
        y1 = fmaf(wm, st[0][tid + k], fmaf(wa, st[1][tid + k], y1));
        y2 = fmaf(wm, st[2][tid + k], fmaf(wa, st[3][tid + k], y2));
    }
    float t1 = fmaxf(y1 * inv + bb2, 0.f);
    float t2 = fmaxf(y2 * inv + bb2, 0.f);
    float A1 = 1.0f / (1.0f + expf(-t1));
    float A2 = 1.0f / (1.0f + expf(-t2));

    const unsigned short* fb = f16 + (size_t)b * CH * LL + l0 + tid;
    float* ob = out + (size_t)b * CH * LL + l0 + tid;
    #pragma unroll 4
    for (int c = 0; c < CH; ++c) {
        float v = h2f(fb[(size_t)c * LL]) * cms[c];
        float a = (mks[c] > 0.5f) ? A1 : A2;
        ob[(size_t)c * LL] = v * a;
    }
}

// ---------------------------------------------------------------------------
// FALLBACK path (ws too small): f fp32 in d_out; stats+gate -> A1/A2 arrays;
// separate final multiply in place. (Identical to the round-6 kernels.)
// ---------------------------------------------------------------------------
__global__ __launch_bounds__(256)
void stats_gate_kernel(const float* __restrict__ f, const float* __restrict__ cm,
                       const float* __restrict__ maskv, const float* __restrict__ sa_w,
                       const float* __restrict__ sabn_g, const float* __restrict__ sabn_b,
                       const float* __restrict__ sabn_m, const float* __restrict__ sabn_v,
                       float* __restrict__ A1, float* __restrict__ A2)
{
    __shared__ float cms[CH], mks[CH];
    __shared__ float st[4][264];
    int b   = blockIdx.x;
    int l0  = blockIdx.y * 256;
    int tid = threadIdx.x;
    if (tid < CH) { cms[tid] = cm[b * CH + tid]; mks[tid] = maskv[b * CH + tid]; }
    __syncthreads();

    for (int idx = tid; idx < 262; idx += 256) {
        int l = l0 - 3 + idx;
        float cmx = 0.f, csm = 0.f, smx = 0.f, ssm = 0.f;
        if (l >= 0 && l < LL) {
            const float* fb = f + (size_t)b * CH * LL + l;
            #pragma unroll 4
            for (int c = 0; c < CH; ++c) {
                float v  = fb[(size_t)c * LL] * cms[c];
                float mk = mks[c];
                float vs = v * mk;
                float vu = v - vs;
                cmx = fmaxf(cmx, vs);
                smx = fmaxf(smx, vu);
                csm += vs;
                ssm += vu;
            }
        }
        st[0][idx] = cmx;
        st[1][idx] = csm * (1.0f / KCR);
        st[2][idx] = smx;
        st[3][idx] = ssm * (1.0f / (CH - KCR));
    }
    __syncthreads();

    float inv = sabn_g[0] * rsqrtf(sabn_v[0] + EPSV);
    float bb2 = sabn_b[0] - sabn_m[0] * inv;
    float y1 = 0.f, y2 = 0.f;
    #pragma unroll
    for (int k = 0; k < 7; ++k) {
        float wm = sa_w[k], wa = sa_w[7 + k];
        y1 = fmaf(wm, st[0][tid + k], fmaf(wa, st[1][tid + k], y1));
        y2 = fmaf(wm, st[2][tid + k], fmaf(wa, st[3][tid + k], y2));
    }
    float t1 = fmaxf(y1 * inv + bb2, 0.f);
    float t2 = fmaxf(y2 * inv + bb2, 0.f);
    A1[b * LL + l0 + tid] = 1.0f / (1.0f + expf(-t1));
    A2[b * LL + l0 + tid] = 1.0f / (1.0f + expf(-t2));
}

__global__ __launch_bounds__(256)
void final_kernel(float* __restrict__ out, const float* __restrict__ cm,
                  const float* __restrict__ maskv,
                  const float* __restrict__ A1, const float* __restrict__ A2)
{
    int g = blockIdx.x * 256 + threadIdx.x;
    size_t idx4 = (size_t)g * 4;
    int l  = (int)(idx4 & (LL - 1));
    int bc = (int)(idx4 >> 14);
    int b  = bc >> 7;
    float cmv = cm[bc];
    float mk  = maskv[bc];
    const float* Ap = (mk > 0.5f) ? A1 : A2;
    float4 a = *(const float4*)&Ap[b * LL + l];
    float4 v = *(const float4*)&out[idx4];
    v.x *= cmv * a.x;
    v.y *= cmv * a.y;
    v.z *= cmv * a.z;
    v.w *= cmv * a.w;
    *(float4*)&out[idx4] = v;
}

extern "C" void kernel_launch(void* const* d_in, const int* in_sizes, int n_in,
                              void* d_out, int out_size, void* d_ws, size_t ws_size,
                              hipStream_t stream)
{
    const float* x      = (const float*)d_in[0];
    const float* conv_w = (const float*)d_in[1];
    const float* conv_b = (const float*)d_in[2];
    const float* bn_g   = (const float*)d_in[3];
    const float* bn_b   = (const float*)d_in[4];
    const float* bn_m   = (const float*)d_in[5];
    const float* bn_v   = (const float*)d_in[6];
    const float* alpha  = (const float*)d_in[7];
    const float* beta   = (const float*)d_in[8];
    const float* ca_w   = (const float*)d_in[9];
    const float* ca_b   = (const float*)d_in[10];
    const float* sa_w   = (const float*)d_in[11];
    const float* sabn_g = (const float*)d_in[12];
    const float* sabn_b = (const float*)d_in[13];
    const float* sabn_m = (const float*)d_in[14];
    const float* sabn_v = (const float*)d_in[15];

    float* out = (float*)d_out;
    float* ws  = (float*)d_ws;

    unsigned short* wpack = (unsigned short*)(ws + OFF_WPACK);
    float* bias2 = ws + OFF_BIAS2;
    float* psum  = ws + OFF_PSUM;
    float* pmax  = ws + OFF_PMAX;
    float* cmv_  = ws + OFF_CM;
    float* mskv  = ws + OFF_MASK;
    float* A1p   = ws + OFF_A1;
    float* A2p   = ws + OFF_A2;
    unsigned short* f16p = (unsigned short*)(ws + OFF_F16);

    const bool fp16_path = (ws_size >= WS_NEED_FLOATS * sizeof(float));

    prep_kernel<<<320, 256, 0, stream>>>(conv_w, conv_b, bn_g, bn_b, bn_m, bn_v, wpack, bias2);

    if (fp16_path) {
        conv_mfma_kernel<true><<<dim3(BB, 128), 256, 0, stream>>>(x, wpack, bias2,
                                                                  (void*)f16p, psum, pmax);
        chan_kernel<<<BB, CH, 0, stream>>>(psum, pmax, alpha, beta, ca_w, ca_b, cmv_, mskv);
        sgf_kernel<<<dim3(64, BB), 256, 0, stream>>>(f16p, out, cmv_, mskv, sa_w,
                                                     sabn_g, sabn_b, sabn_m, sabn_v);
    } else {
        conv_mfma_kernel<false><<<dim3(BB, 128), 256, 0, stream>>>(x, wpack, bias2,
                                                                   (void*)out, psum, pmax);
        chan_kernel<<<BB, CH, 0, stream>>>(psum, pmax, alpha, beta, ca_w, ca_b, cmv_, mskv);
        stats_gate_kernel<<<dim3(BB, 64), 256, 0, stream>>>(out, cmv_, mskv, sa_w,
                                                            sabn_g, sabn_b, sabn_m, sabn_v, A1p, A2p);
        final_kernel<<<(BB * CH * LL / 4 + 255) / 256, 256, 0, stream>>>(out, cmv_, mskv, A1p, A2p);
    }
}

// Round 8
// 167.690 us; speedup vs baseline: 4.3090x; 1.0016x over previous
//
#include <hip/hip_runtime.h>
#include <hip/hip_bf16.h>
#include <math.h>

#define BB 16
#define IC 64
#define CH 128
#define LL 16384
#define KS 5
#define CAK 5
#define KCR 76
#define EPSV 1e-5f
#define NLT2 256          // psum/pmax partials per (b,c): 128 l-tiles x 2 half-waves

typedef short bf16x8 __attribute__((ext_vector_type(8)));
typedef float f32x16 __attribute__((ext_vector_type(16)));

// ---- workspace layout (in floats) ----
#define OFF_WPACK 0                          // 81920 ushort = 40960 floats
#define OFF_BIAS2 40960                      // 128
#define OFF_PSUM  (OFF_BIAS2 + CH)           // 16*128*256 = 524288
#define OFF_PMAX  (OFF_PSUM + BB*CH*NLT2)
#define OFF_CM    (OFF_PMAX + BB*CH*NLT2)    // 2048
#define OFF_MASK  (OFF_CM + BB*CH)
#define OFF_A1    (OFF_MASK + BB*CH)         // 262144 (fallback path only)
#define OFF_A2    (OFF_A1 + BB*LL)
#define OFF_F16   (OFF_A2 + BB*LL)           // fp16 f: BB*CH*LL ushorts = 16Mi floats
#define WS_NEED_FLOATS ((size_t)OFF_F16 + (size_t)BB * CH * LL / 2)

__device__ __forceinline__ unsigned short f2bf(float f) {
    union { float f; unsigned u; } v; v.f = f;
    return (unsigned short)((v.u + 0x7FFFu + ((v.u >> 16) & 1u)) >> 16);
}
__device__ __forceinline__ float bf2f(unsigned short h) {
    union { unsigned u; float f; } v; v.u = ((unsigned)h) << 16;
    return v.f;
}
__device__ __forceinline__ unsigned short f2h(float f) {
    _Float16 h = (_Float16)f;
    return __builtin_bit_cast(unsigned short, h);
}
__device__ __forceinline__ float h2f(unsigned short u) {
    _Float16 h = __builtin_bit_cast(_Float16, u);
    return (float)h;
}

// DPP lane-shift (VALU pipe, no LDS). bound_ctrl=true: invalid lanes -> 0.
template<int CTRL>
__device__ __forceinline__ float dppf(float v) {
    return __builtin_bit_cast(float,
        __builtin_amdgcn_update_dpp(0, __builtin_bit_cast(int, v), CTRL, 0xF, 0xF, true));
}
// 32-lane-half reduction: totals land in lanes 31 and 63. f>=0 so zero-fill ok.
__device__ __forceinline__ float dpp_sum32(float s) {
    s += dppf<0x111>(s);   // row_shr:1
    s += dppf<0x112>(s);   // row_shr:2
    s += dppf<0x114>(s);   // row_shr:4
    s += dppf<0x118>(s);   // row_shr:8
    s += dppf<0x142>(s);   // row_bcast:15
    return s;
}
__device__ __forceinline__ float dpp_max32(float m) {
    m = fmaxf(m, dppf<0x111>(m));
    m = fmaxf(m, dppf<0x112>(m));
    m = fmaxf(m, dppf<0x114>(m));
    m = fmaxf(m, dppf<0x118>(m));
    m = fmaxf(m, dppf<0x142>(m));
    return m;
}

// ---------------------------------------------------------------------------
// Prep: fold BN scale into conv weights, split into bf16 hi/lo, pack in exact
// per-lane MFMA A-fragment order:
//   wpack[((((ver*2+ch2)*2+mt)*20+s)*64+ln)*8+j]
//     c = ch2*64 + mt*32 + (ln&31); kk = s>>2; i = (s&3)*16 + (ln>>5)*8 + j
// ---------------------------------------------------------------------------
__global__ void prep_kernel(const float* __restrict__ conv_w, const float* __restrict__ conv_b,
                            const float* __restrict__ bn_g, const float* __restrict__ bn_b,
                            const float* __restrict__ bn_m, const float* __restrict__ bn_v,
                            unsigned short* __restrict__ wpack, float* __restrict__ bias2)
{
    int e = blockIdx.x * 256 + threadIdx.x;
    if (e < 8 * 20 * 64 * 8) {
        int j    = e & 7;
        int ln   = (e >> 3) & 63;
        int rest = e >> 9;              // 0..159
        int s    = rest % 20;
        int mt   = (rest / 20) & 1;
        int ch2  = (rest / 40) & 1;
        int ver  = rest / 80;
        int c  = ch2 * 64 + mt * 32 + (ln & 31);
        int kk = s >> 2;
        int i  = (s & 3) * 16 + (ln >> 5) * 8 + j;
        float inv = bn_g[c] * rsqrtf(bn_v[c] + EPSV);
        float w = conv_w[(c * IC + i) * KS + kk] * inv;
        unsigned short h = f2bf(w);
        wpack[e] = (ver == 0) ? h : f2bf(w - bf2f(h));
    }
    if (e < CH) {
        float inv = bn_g[e] * rsqrtf(bn_v[e] + EPSV);
        bias2[e] = (conv_b[e] - bn_m[e]) * inv + bn_b[e];
    }
}

// ---------------------------------------------------------------------------
// Split-bf16 MFMA conv + BN + ReLU -> f (fp16 into ws, or fp32 into d_out on
// the fallback path) + per-channel partial sum/max (DPP, fp32 pre-quant).
// Block = 128c x 128l, 4 waves of (64c x 64l). LDS tile xs[136][128] =
// [64 hi bf16 | 64 lo bf16], 16B chunks XOR-swizzled by (row&7).
// f = wh*xh + wh*xl + wl*xh  (fp32 MFMA accumulate).
// ---------------------------------------------------------------------------
template<bool F16OUT>
__global__ __launch_bounds__(256, 4)
void conv_mfma_kernel(const float* __restrict__ x,
                      const unsigned short* __restrict__ wpack,
                      const float* __restrict__ bias2,
                      void* __restrict__ fout,
                      float* __restrict__ psum, float* __restrict__ pmax)
{
    __shared__ unsigned short xs[136 * 128];   // 34,816 B -> 4 blocks/CU
    const int b   = blockIdx.x;
    const int lt  = blockIdx.y;
    const int l0  = lt * 128;
    const int tid = threadIdx.x;
    const int ln  = tid & 63;
    const int wv  = __builtin_amdgcn_readfirstlane(tid >> 6);

    // ---- staging: wave wv owns i in [wv*16, wv*16+16); lane = row (l) ----
    const float* xb = x + (size_t)b * (IC * LL);
    const int ibase = wv * 16;
    #pragma unroll
    for (int g = 0; g < 3; ++g) {
        int row = g * 64 + ln;           // 0..191; valid rows < 136
        int l   = l0 - 4 + row;
        if (row < 136) {
            bool vl = (l >= 0) && (l < LL);
            float v[16];
            #pragma unroll
            for (int q = 0; q < 16; ++q)
                v[q] = vl ? xb[(size_t)(ibase + q) * LL + l] : 0.0f;
            int rs = row & 7;
            #pragma unroll
            for (int q2 = 0; q2 < 4; ++q2) {
                unsigned short h[4], lo[4];
                #pragma unroll
                for (int j = 0; j < 4; ++j) {
                    float vv = v[q2 * 4 + j];
                    h[j]  = f2bf(vv);
                    lo[j] = f2bf(vv - bf2f(h[j]));
                }
                int i0   = ibase + q2 * 4;
                int cc   = (i0 >> 3) ^ rs;
                int epos = row * 128 + cc * 8 + (i0 & 7);
                uint2 wh, wl;
                wh.x = (unsigned)h[0]  | ((unsigned)h[1]  << 16);
                wh.y = (unsigned)h[2]  | ((unsigned)h[3]  << 16);
                wl.x = (unsigned)lo[0] | ((unsigned)lo[1] << 16);
                wl.y = (unsigned)lo[2] | ((unsigned)lo[3] << 16);
                *(uint2*)&xs[epos]      = wh;
                *(uint2*)&xs[epos + 64] = wl;
            }
        }
    }
    __syncthreads();

    const int ch2  = wv >> 1;   // c-half: 0 -> c 0..63, 1 -> 64..127
    const int lh   = wv & 1;    // l-half within the 128-l tile
    const int ln31 = ln & 31;
    const int hi   = ln >> 5;
    const int rowbase = lh * 64 + ln31 + 2;

    // A-fragment stream pointers (wpack is L2-hot, 160 KB)
    const unsigned short* wp  = wpack + (size_t)ln * 8;
    const unsigned short* pA0 = wp + (size_t)((ch2 * 2 + 0) * 20) * 512;       // wh, mt0
    const unsigned short* pA1 = wp + (size_t)((ch2 * 2 + 1) * 20) * 512;       // wh, mt1
    const unsigned short* pA2 = wp + (size_t)(((2 + ch2) * 2 + 0) * 20) * 512; // wl, mt0
    const unsigned short* pA3 = wp + (size_t)(((2 + ch2) * 2 + 1) * 20) * 512; // wl, mt1

    f32x16 acc[2][2];
    #pragma unroll
    for (int mt = 0; mt < 2; ++mt)
        #pragma unroll
        for (int nt = 0; nt < 2; ++nt)
            #pragma unroll
            for (int r = 0; r < 16; ++r) acc[mt][nt][r] = 0.0f;

    auto loadA = [&](bf16x8* Av, int s) {
        Av[0] = *(const bf16x8*)(pA0 + (size_t)s * 512);
        Av[1] = *(const bf16x8*)(pA1 + (size_t)s * 512);
        Av[2] = *(const bf16x8*)(pA2 + (size_t)s * 512);
        Av[3] = *(const bf16x8*)(pA3 + (size_t)s * 512);
    };
    auto loadB = [&](bf16x8* Bv, int s) {
        int kk = s >> 2, iq = s & 3;
        int r0 = rowbase + kk;
        int r1 = r0 + 32;
        int c0 = ((iq << 1) + hi) ^ (r0 & 7);
        int c1 = ((iq << 1) + hi) ^ (r1 & 7);
        Bv[0] = *(const bf16x8*)&xs[r0 * 128 + c0 * 8];        // bh, nt0
        Bv[1] = *(const bf16x8*)&xs[r0 * 128 + 64 + c0 * 8];   // bl, nt0
        Bv[2] = *(const bf16x8*)&xs[r1 * 128 + c1 * 8];        // bh, nt1
        Bv[3] = *(const bf16x8*)&xs[r1 * 128 + 64 + c1 * 8];   // bl, nt1
    };
    // Interleaved across the 4 accumulators: same-acc dep distance = 4.
    auto compute = [&](const bf16x8* Av, const bf16x8* Bv) {
        acc[0][0] = __builtin_amdgcn_mfma_f32_32x32x16_bf16(Av[0], Bv[0], acc[0][0], 0, 0, 0);
        acc[1][0] = __builtin_amdgcn_mfma_f32_32x32x16_bf16(Av[1], Bv[0], acc[1][0], 0, 0, 0);
        acc[0][1] = __builtin_amdgcn_mfma_f32_32x32x16_bf16(Av[0], Bv[2], acc[0][1], 0, 0, 0);
        acc[1][1] = __builtin_amdgcn_mfma_f32_32x32x16_bf16(Av[1], Bv[2], acc[1][1], 0, 0, 0);
        acc[0][0] = __builtin_amdgcn_mfma_f32_32x32x16_bf16(Av[0], Bv[1], acc[0][0], 0, 0, 0);
        acc[1][0] = __builtin_amdgcn_mfma_f32_32x32x16_bf16(Av[1], Bv[1], acc[1][0], 0, 0, 0);
        acc[0][1] = __builtin_amdgcn_mfma_f32_32x32x16_bf16(Av[0], Bv[3], acc[0][1], 0, 0, 0);
        acc[1][1] = __builtin_amdgcn_mfma_f32_32x32x16_bf16(Av[1], Bv[3], acc[1][1], 0, 0, 0);
        acc[0][0] = __builtin_amdgcn_mfma_f32_32x32x16_bf16(Av[2], Bv[0], acc[0][0], 0, 0, 0);
        acc[1][0] = __builtin_amdgcn_mfma_f32_32x32x16_bf16(Av[3], Bv[0], acc[1][0], 0, 0, 0);
        acc[0][1] = __builtin_amdgcn_mfma_f32_32x32x16_bf16(Av[2], Bv[2], acc[0][1], 0, 0, 0);
        acc[1][1] = __builtin_amdgcn_mfma_f32_32x32x16_bf16(Av[3], Bv[2], acc[1][1], 0, 0, 0);
    };

    // ---- main loop: 3-deep A ring, 2-deep B ring ----
    bf16x8 Ar[3][4], Br[2][4];
    loadA(Ar[0], 0); loadA(Ar[1], 1); loadA(Ar[2], 2);
    loadB(Br[0], 0); loadB(Br[1], 1);
    #pragma unroll
    for (int s = 0; s < 20; ++s) {
        compute(Ar[s % 3], Br[s & 1]);
        if (s + 3 < 20) loadA(Ar[s % 3], s + 3);
        if (s + 2 < 20) loadB(Br[s & 1], s + 2);
    }

    // ---- epilogue: bias + relu, store f, per-channel partial sum/max ----
    // D mapping (32x32): col(l) = ln&31, row(c) = (r&3) + 8*(r>>2) + 4*(ln>>5)
    const int lgbase = l0 + lh * 64 + ln31;
    #pragma unroll
    for (int mt = 0; mt < 2; ++mt) {
        #pragma unroll
        for (int nt = 0; nt < 2; ++nt) {
            #pragma unroll
            for (int r = 0; r < 16; ++r) {
                int c = ch2 * 64 + mt * 32 + (r & 3) + 8 * (r >> 2) + 4 * hi;
                float fv = fmaxf(acc[mt][nt][r] + bias2[c], 0.0f);
                size_t off = ((size_t)(b * CH + c)) * LL + lgbase + nt * 32;
                if constexpr (F16OUT) ((unsigned short*)fout)[off] = f2h(fv);
                else                  ((float*)fout)[off] = fv;
                acc[mt][nt][r] = fv;
            }
        }
    }
    // per-channel partial sum/max over this wave's 64 l's, via DPP (no LDS).
    // Totals land in lanes 31 (hi=0 c's) and 63 (hi=1 c's).
    #pragma unroll
    for (int mt = 0; mt < 2; ++mt) {
        #pragma unroll
        for (int r = 0; r < 16; ++r) {
            float s = dpp_sum32(acc[mt][0][r] + acc[mt][1][r]);
            float m = dpp_max32(fmaxf(acc[mt][0][r], acc[mt][1][r]));
            if (ln31 == 31) {
                int c   = ch2 * 64 + mt * 32 + (r & 3) + 8 * (r >> 2) + 4 * hi;
                int lt2 = lt * 2 + lh;
                psum[(b * CH + c) * NLT2 + lt2] = s;
                pmax[(b * CH + c) * NLT2 + lt2] = m;
            }
        }
    }
}

// ---------------------------------------------------------------------------
// Per-batch: finish L-reductions, channel attention, top-K mask (rank count,
// ties by lower index to match jax.lax.top_k). Grid: B x 128 threads.
// ---------------------------------------------------------------------------
__global__ void chan_kernel(const float* __restrict__ psum, const float* __restrict__ pmax,
                            const float* __restrict__ alpha, const float* __restrict__ beta,
                            const float* __restrict__ ca_w, const float* __restrict__ ca_b,
                            float* __restrict__ cm, float* __restrict__ maskv)
{
    int b = blockIdx.x;
    int c = threadIdx.x;   // 128
    const float* ps = psum + (b * CH + c) * NLT2;
    const float* pm = pmax + (b * CH + c) * NLT2;
    float s = 0.0f, m = 0.0f;
    for (int t = 0; t < NLT2; ++t) { s += ps[t]; m = fmaxf(m, pm[t]); }
    float favg = s * (1.0f / LL);
    float fadd = (alpha[0] + 0.5f) * favg + (beta[0] + 0.5f) * m;

    __shared__ float fa[CH];
    __shared__ float cms[CH];
    fa[c] = fadd;
    __syncthreads();

    float z = ca_b[0];
    #pragma unroll
    for (int k = 0; k < CAK; ++k) {
        int cc = c + k - 2;
        float v = (cc >= 0 && cc < CH) ? fa[cc] : 0.0f;
        z = fmaf(ca_w[k], v, z);
    }
    float cmv = 1.0f / (1.0f + expf(-z));
    cms[c] = cmv;
    __syncthreads();

    int rank = 0;
    for (int cc = 0; cc < CH; ++cc) {
        float o = cms[cc];
        rank += (o > cmv || (o == cmv && cc < c)) ? 1 : 0;
    }
    cm[b * CH + c] = cmv;
    maskv[b * CH + c] = (rank < KCR) ? 1.0f : 0.0f;
}

// ---------------------------------------------------------------------------
// FP16 path: fused stats + gate + final, VECTORIZED x2 along l.
// Block = (b, 512 l), thread owns 2 adjacent l's (uint f16 loads, float2 out
// stores). Phase 1: per-l group stats of crf = f16*cm into st[4][518] (6 halo
// slots computed scalar by threads 0..5; f16 is read-only -> no race).
// Phase 2: 7-tap gate conv + BN + ReLU + sigmoid, out = f16*cm*(mask?A1:A2).
// ---------------------------------------------------------------------------
__global__ __launch_bounds__(256)
void sgf_kernel(const unsigned short* __restrict__ f16, float* __restrict__ out,
                const float* __restrict__ cm, const float* __restrict__ maskv,
                const float* __restrict__ sa_w,
                const float* __restrict__ sabn_g, const float* __restrict__ sabn_b,
                const float* __restrict__ sabn_m, const float* __restrict__ sabn_v)
{
    __shared__ float cms[CH], mks[CH];
    __shared__ float st[4][520];                  // 518 used
    const int g   = blockIdx.x;    // 0..31 (512-l tile)
    const int b   = blockIdx.y;
    const int l0  = g * 512;
    const int tid = threadIdx.x;
    if (tid < CH) { cms[tid] = cm[b * CH + tid]; mks[tid] = maskv[b * CH + tid]; }
    __syncthreads();

    // ---- interior stats: 2 adjacent l per thread, uint loads ----
    {
        const unsigned short* fb = f16 + (size_t)b * CH * LL + l0 + 2 * tid;
        float cmx0 = 0.f, csm0 = 0.f, smx0 = 0.f, ssm0 = 0.f;
        float cmx1 = 0.f, csm1 = 0.f, smx1 = 0.f, ssm1 = 0.f;
        #pragma unroll 4
        for (int c = 0; c < CH; ++c) {
            unsigned pr = *(const unsigned*)(fb + (size_t)c * LL);
            float cmc = cms[c], mk = mks[c];
            float v0 = h2f((unsigned short)(pr & 0xFFFFu)) * cmc;
            float v1 = h2f((unsigned short)(pr >> 16)) * cmc;
            float vs0 = v0 * mk, vu0 = v0 - vs0;
            float vs1 = v1 * mk, vu1 = v1 - vs1;
            cmx0 = fmaxf(cmx0, vs0); smx0 = fmaxf(smx0, vu0); csm0 += vs0; ssm0 += vu0;
            cmx1 = fmaxf(cmx1, vs1); smx1 = fmaxf(smx1, vu1); csm1 += vs1; ssm1 += vu1;
        }
        int s0 = 3 + 2 * tid;
        st[0][s0] = cmx0;                  st[0][s0 + 1] = cmx1;
        st[1][s0] = csm0 * (1.0f / KCR);   st[1][s0 + 1] = csm1 * (1.0f / KCR);
        st[2][s0] = smx0;                  st[2][s0 + 1] = smx1;
        st[3][s0] = ssm0 * (1.0f / (CH - KCR));
        st[3][s0 + 1] = ssm1 * (1.0f / (CH - KCR));
    }
    // ---- halo stats: slots 0..2 and 515..517, scalar (threads 0..5) ----
    if (tid < 6) {
        int slot = (tid < 3) ? tid : 515 + (tid - 3);
        int l = l0 - 3 + slot;
        float cmx = 0.f, csm = 0.f, smx = 0.f, ssm = 0.f;
        if (l >= 0 && l < LL) {
            const unsigned short* fb = f16 + (size_t)b * CH * LL + l;
            for (int c = 0; c < CH; ++c) {
                float v  = h2f(fb[(size_t)c * LL]) * cms[c];
                float mk = mks[c];
                float vs = v * mk, vu = v - vs;
                cmx = fmaxf(cmx, vs); smx = fmaxf(smx, vu);
                csm += vs; ssm += vu;
            }
        }
        st[0][slot] = cmx;
        st[1][slot] = csm * (1.0f / KCR);
        st[2][slot] = smx;
        st[3][slot] = ssm * (1.0f / (CH - KCR));
    }
    __syncthreads();

    // ---- gate for both l's ----
    float inv = sabn_g[0] * rsqrtf(sabn_v[0] + EPSV);
    float bb2 = sabn_b[0] - sabn_m[0] * inv;
    float y1a = 0.f, y2a = 0.f, y1b = 0.f, y2b = 0.f;
    #pragma unroll
    for (int k = 0; k < 7; ++k) {
        float wm = sa_w[k], wa = sa_w[7 + k];
        int s0 = 2 * tid + k;
        y1a = fmaf(wm, st[0][s0],     fmaf(wa, st[1][s0],     y1a));
        y2a = fmaf(wm, st[2][s0],     fmaf(wa, st[3][s0],     y2a));
        y1b = fmaf(wm, st[0][s0 + 1], fmaf(wa, st[1][s0 + 1], y1b));
        y2b = fmaf(wm, st[2][s0 + 1], fmaf(wa, st[3][s0 + 1], y2b));
    }
    float A1a = 1.0f / (1.0f + expf(-fmaxf(y1a * inv + bb2, 0.f)));
    float A2a = 1.0f / (1.0f + expf(-fmaxf(y2a * inv + bb2, 0.f)));
    float A1b = 1.0f / (1.0f + expf(-fmaxf(y1b * inv + bb2, 0.f)));
    float A2b = 1.0f / (1.0f + expf(-fmaxf(y2b * inv + bb2, 0.f)));

    // ---- final: out = f*cm*(mask?A1:A2), float2 stores ----
    const unsigned short* fb = f16 + (size_t)b * CH * LL + l0 + 2 * tid;
    float* ob = out + (size_t)b * CH * LL + l0 + 2 * tid;
    #pragma unroll 4
    for (int c = 0; c < CH; ++c) {
        unsigned pr = *(const unsigned*)(fb + (size_t)c * LL);
        float cmc = cms[c];
        float v0 = h2f((unsigned short)(pr & 0xFFFFu)) * cmc;
        float v1 = h2f((unsigned short)(pr >> 16)) * cmc;
        bool sel = (mks[c] > 0.5f);
        float2 w;
        w.x = v0 * (sel ? A1a : A2a);
        w.y = v1 * (sel ? A1b : A2b);
        *(float2*)(ob + (size_t)c * LL) = w;
    }
}

// ---------------------------------------------------------------------------
// FALLBACK path (ws too small): f fp32 in d_out; stats+gate -> A1/A2 arrays;
// separate final multiply in place.
// ---------------------------------------------------------------------------
__global__ __launch_bounds__(256)
void stats_gate_kernel(const float* __restrict__ f, const float* __restrict__ cm,
                       const float* __restrict__ maskv, const float* __restrict__ sa_w,
                       const float* __restrict__ sabn_g, const float* __restrict__ sabn_b,
                       const float* __restrict__ sabn_m, const float* __restrict__ sabn_v,
                       float* __restrict__ A1, float* __restrict__ A2)
{
    __shared__ float cms[CH], mks[CH];
    __shared__ float st[4][264];
    int b   = blockIdx.x;
    int l0  = blockIdx.y * 256;
    int tid = threadIdx.x;
    if (tid < CH) { cms[tid] = cm[b * CH + tid]; mks[tid] = maskv[b * CH + tid]; }
    __syncthreads();

    for (int idx = tid; idx < 262; idx += 256) {
        int l = l0 - 3 + idx;
        float cmx = 0.f, csm = 0.f, smx = 0.f, ssm = 0.f;
        if (l >= 0 && l < LL) {
            const float* fb = f + (size_t)b * CH * LL + l;
            #pragma unroll 4
            for (int c = 0; c < CH; ++c) {
                float v  = fb[(size_t)c * LL] * cms[c];
                float mk = mks[c];
                float vs = v * mk;
                float vu = v - vs;
                cmx = fmaxf(cmx, vs);
                smx = fmaxf(smx, vu);
                csm += vs;
                ssm += vu;
            }
        }
        st[0][idx] = cmx;
        st[1][idx] = csm * (1.0f / KCR);
        st[2][idx] = smx;
        st[3][idx] = ssm * (1.0f / (CH - KCR));
    }
    __syncthreads();

    float inv = sabn_g[0] * rsqrtf(sabn_v[0] + EPSV);
    float bb2 = sabn_b[0] - sabn_m[0] * inv;
    float y1 = 0.f, y2 = 0.f;
    #pragma unroll
    for (int k = 0; k < 7; ++k) {
        float wm = sa_w[k], wa = sa_w[7 + k];
        y1 = fmaf(wm, st[0][tid + k], fmaf(wa, st[1][tid + k], y1));
        y2 = fmaf(wm, st[2][tid + k], fmaf(wa, st[3][tid + k], y2));
    }
    float t1 = fmaxf(y1 * inv + bb2, 0.f);
    float t2 = fmaxf(y2 * inv + bb2, 0.f);
    A1[b * LL + l0 + tid] = 1.0f / (1.0f + expf(-t1));
    A2[b * LL + l0 + tid] = 1.0f / (1.0f + expf(-t2));
}

__global__ __launch_bounds__(256)
void final_kernel(float* __restrict__ out, const float* __restrict__ cm,
                  const float* __restrict__ maskv,
                  const float* __restrict__ A1, const float* __restrict__ A2)
{
    int g = blockIdx.x * 256 + threadIdx.x;
    size_t idx4 = (size_t)g * 4;
    int l  = (int)(idx4 & (LL - 1));
    int bc = (int)(idx4 >> 14);
    int b  = bc >> 7;
    float cmv = cm[bc];
    float mk  = maskv[bc];
    const float* Ap = (mk > 0.5f) ? A1 : A2;
    float4 a = *(const float4*)&Ap[b * LL + l];
    float4 v = *(const float4*)&out[idx4];
    v.x *= cmv * a.x;
    v.y *= cmv * a.y;
    v.z *= cmv * a.z;
    v.w *= cmv * a.w;
    *(float4*)&out[idx4] = v;
}

extern "C" void kernel_launch(void* const* d_in, const int* in_sizes, int n_in,
                              void* d_out, int out_size, void* d_ws, size_t ws_size,
                              hipStream_t stream)
{
    const float* x      = (const float*)d_in[0];
    const float* conv_w = (const float*)d_in[1];
    const float* conv_b = (const float*)d_in[2];
    const float* bn_g   = (const float*)d_in[3];
    const float* bn_b   = (const float*)d_in[4];
    const float* bn_m   = (const float*)d_in[5];
    const float* bn_v   = (const float*)d_in[6];
    const float* alpha  = (const float*)d_in[7];
    const float* beta   = (const float*)d_in[8];
    const float* ca_w   = (const float*)d_in[9];
    const float* ca_b   = (const float*)d_in[10];
    const float* sa_w   = (const float*)d_in[11];
    const float* sabn_g = (const float*)d_in[12];
    const float* sabn_b = (const float*)d_in[13];
    const float* sabn_m = (const float*)d_in[14];
    const float* sabn_v = (const float*)d_in[15];

    float* out = (float*)d_out;
    float* ws  = (float*)d_ws;

    unsigned short* wpack = (unsigned short*)(ws + OFF_WPACK);
    float* bias2 = ws + OFF_BIAS2;
    float* psum  = ws + OFF_PSUM;
    float* pmax  = ws + OFF_PMAX;
    float* cmv_  = ws + OFF_CM;
    float* mskv  = ws + OFF_MASK;
    float* A1p   = ws + OFF_A1;
    float* A2p   = ws + OFF_A2;
    unsigned short* f16p = (unsigned short*)(ws + OFF_F16);

    const bool fp16_path = (ws_size >= WS_NEED_FLOATS * sizeof(float));

    prep_kernel<<<320, 256, 0, stream>>>(conv_w, conv_b, bn_g, bn_b, bn_m, bn_v, wpack, bias2);

    if (fp16_path) {
        conv_mfma_kernel<true><<<dim3(BB, 128), 256, 0, stream>>>(x, wpack, bias2,
                                                                  (void*)f16p, psum, pmax);
        chan_kernel<<<BB, CH, 0, stream>>>(psum, pmax, alpha, beta, ca_w, ca_b, cmv_, mskv);
        sgf_kernel<<<dim3(32, BB), 256, 0, stream>>>(f16p, out, cmv_, mskv, sa_w,
                                                     sabn_g, sabn_b, sabn_m, sabn_v);
    } else {
        conv_mfma_kernel<false><<<dim3(BB, 128), 256, 0, stream>>>(x, wpack, bias2,
                                                                   (void*)out, psum, pmax);
        chan_kernel<<<BB, CH, 0, stream>>>(psum, pmax, alpha, beta, ca_w, ca_b, cmv_, mskv);
        stats_gate_kernel<<<dim3(BB, 64), 256, 0, stream>>>(out, cmv_, mskv, sa_w,
                                                            sabn_g, sabn_b, sabn_m, sabn_v, A1p, A2p);
        final_kernel<<<(BB * CH * LL / 4 + 255) / 256, 256, 0, stream>>>(out, cmv_, mskv, A1p, A2p);
    }
}